// Round 5
// baseline (6247.271 us; speedup 1.0000x reference)
//
#include <hip/hip_runtime.h>

typedef unsigned short u16;
typedef __attribute__((ext_vector_type(8))) __bf16 bf16x8;
typedef __attribute__((ext_vector_type(4))) float f32x4;

typedef __attribute__((address_space(1))) const void gvoid_t;
typedef __attribute__((address_space(3))) void lvoid_t;

enum { E_CADD = 1, E_BIAS = 2, E_RELU = 4, E_AFF = 8, E_WBF = 16, E_WF32 = 32, E_FINAL = 64 };

#define GRID 512
#define THREADS 512

static __device__ __forceinline__ u16 f2bf(float f) {
  unsigned u = __float_as_uint(f);
  u += 0x7fffu + ((u >> 16) & 1u);
  return (u16)(u >> 16);
}
static __device__ __forceinline__ float bf2f(u16 h) {
  return __uint_as_float(((unsigned)h) << 16);
}

struct MegaArgs {
  const float *nonvis, *fm, *prior, *W1, *b1, *g1, *be1, *m1, *v1;
  const float *W2, *b2, *g2, *be2, *m2, *v2, *Wk, *Uk, *bi, *br;
  const float *ct1w, *ct1b, *ct2w, *ct2b, *ct3w, *ct3b, *ct4w, *ct4b, *Ws, *bs;
  u16 *nonvis_b, *W1nv_t, *W1v_t, *W2t, *Wkt, *Ukt, *Wsnv_t, *Wsv_t;
  u16 *Wp1, *Wp2, *Wp3, *Wp4;
  float *bp1, *bp2, *bp3, *bp4, *scale1, *shift1, *scale2, *shift2, *bs_pad;
  float *P1, *snv, *mx, *mi, *hf;
  u16 *x1, *x2, *hb, *a1, *a2, *a3;
  float *a4, *vis_sum;
  u16 *visb, *vsb, *fmb;
  float *out;
  unsigned *cnt;
  int use_fmb;
};

// ---- device-scope grid barrier: one fetch_add per block, LOAD-spin (no RMW) --
static __device__ __forceinline__ void gbar(unsigned* cnt, unsigned goal) {
  __syncthreads();
  if (threadIdx.x == 0) {
    __threadfence();   // release this block's writes
    __hip_atomic_fetch_add(cnt, 1u, __ATOMIC_ACQ_REL, __HIP_MEMORY_SCOPE_AGENT);
    while (__hip_atomic_load(cnt, __ATOMIC_ACQUIRE, __HIP_MEMORY_SCOPE_AGENT) < goal)
      __builtin_amdgcn_s_sleep(4);
    __threadfence();   // acquire others' writes
  }
  __syncthreads();
}

// -------- 64x128 MFMA GEMM tile, 8 waves, dbuf LDS + XOR swizzle (T2) --------
template <int FLAGS>
static __device__ void gtile(u16* As, u16* Bs,
    const u16* __restrict__ A, const u16* __restrict__ Bt,
    float* __restrict__ Cf, u16* __restrict__ Cb,
    const float* __restrict__ Cadd, const float* __restrict__ bias,
    const float* __restrict__ scale, const float* __restrict__ shift,
    int N, int K, int bx, int by) {
  const int tid = threadIdx.x;
  const int wave = tid >> 6, lane = tid & 63;
  const int bm = by << 6, bn = bx << 7;
  const int lr = lane & 15, lg = lane >> 4;
  const int rx = lr & 7;
  const int wm = (wave >> 2) << 5, wn = (wave & 3) << 5;

  f32x4 acc[2][2] = {};

  auto stage = [&](int buf, int kt) {
    { const int row = tid >> 3;
      const int cg = (tid & 7) ^ (row & 7);
      __builtin_amdgcn_global_load_lds(
          (gvoid_t*)(A + (size_t)(bm + row) * K + kt + (cg << 3)),
          (lvoid_t*)(As + buf * 4096 + wave * 512), 16, 0, 0); }
#pragma unroll
    for (int i = 0; i < 2; ++i) {
      const int li = i * 512 + tid;
      const int row = li >> 3;
      const int cg = (li & 7) ^ (row & 7);
      __builtin_amdgcn_global_load_lds(
          (gvoid_t*)(Bt + (size_t)(bn + row) * K + kt + (cg << 3)),
          (lvoid_t*)(Bs + buf * 8192 + i * 4096 + wave * 512), 16, 0, 0);
    }
  };

  stage(0, 0);
  int buf = 0;
  for (int kt = 0; kt < K; kt += 64) {
    __syncthreads();                       // buf staged; prev reads done
    if (kt + 64 < K) stage(buf ^ 1, kt + 64);
    const u16* Ab = As + buf * 4096;
    const u16* Bb = Bs + buf * 8192;
#pragma unroll
    for (int kk = 0; kk < 64; kk += 32) {
      bf16x8 av[2], bv[2];
#pragma unroll
      for (int mi2 = 0; mi2 < 2; ++mi2)
        av[mi2] = *(const bf16x8*)(Ab + ((wm + mi2 * 16 + lr) << 6) +
                                   ((((kk >> 3) + lg) ^ rx) << 3));
#pragma unroll
      for (int ni = 0; ni < 2; ++ni)
        bv[ni] = *(const bf16x8*)(Bb + ((wn + ni * 16 + lr) << 6) +
                                  ((((kk >> 3) + lg) ^ rx) << 3));
#pragma unroll
      for (int mi2 = 0; mi2 < 2; ++mi2)
#pragma unroll
        for (int ni = 0; ni < 2; ++ni)
          acc[mi2][ni] = __builtin_amdgcn_mfma_f32_16x16x32_bf16(av[mi2], bv[ni], acc[mi2][ni], 0, 0, 0);
    }
    buf ^= 1;
  }

#pragma unroll
  for (int mi2 = 0; mi2 < 2; ++mi2) {
#pragma unroll
    for (int ni = 0; ni < 2; ++ni) {
      const int col = bn + wn + ni * 16 + lr;
#pragma unroll
      for (int r = 0; r < 4; ++r) {
        const int row = bm + wm + mi2 * 16 + (lg << 2) + r;
        float v = acc[mi2][ni][r];
        if (FLAGS & E_FINAL) {
          if (col < 51)
            Cf[row * 51 + col] = v * (1.f / 6.f) + Cadd[(row << 7) + col] + scale[row * 51 + col];
        } else {
          if (FLAGS & E_CADD) v += Cadd[(size_t)row * N + col];
          if (FLAGS & E_BIAS) v += bias[col];
          if (FLAGS & E_RELU) v = fmaxf(v, 0.f);
          if (FLAGS & E_AFF) v = v * scale[col] + shift[col];
          if (FLAGS & E_WF32) Cf[(size_t)row * N + col] = v;
          if (FLAGS & E_WBF) Cb[(size_t)row * N + col] = f2bf(v);
        }
      }
    }
  }
  __syncthreads();                         // protect LDS reuse by next job
}

// -------- phase bodies --------
static __device__ void fm_body(const MegaArgs& a, int b, int st) {
  const int d0 = st << 2;
  const float* p = a.fm + (size_t)b * 102400 + d0;
  float s0 = 0, s1 = 0, s2 = 0, s3 = 0;
  for (int pp = 0; pp < 100; ++pp) {
    const float4 v = *(const float4*)(p + pp * 1024);
    if (a.use_fmb) {
      ushort4 u;
      u.x = f2bf(v.x); u.y = f2bf(v.y); u.z = f2bf(v.z); u.w = f2bf(v.w);
      *(ushort4*)(a.fmb + (size_t)b * 102400 + pp * 1024 + d0) = u;
    }
    s0 += v.x; s1 += v.y; s2 += v.z; s3 += v.w;
  }
  const float inv = 1.0f / 100.0f;
  s0 *= inv; s1 *= inv; s2 *= inv; s3 *= inv;
  const int o = (b << 10) + d0;
  float4 m; m.x = s0; m.y = s1; m.z = s2; m.w = s3;
  *(float4*)(a.vis_sum + o) = m;
  ushort4 u; u.x = f2bf(s0); u.y = f2bf(s1); u.z = f2bf(s2); u.w = f2bf(s3);
  *(ushort4*)(a.visb + o) = u;
}

static __device__ void prep_body(const MegaArgs& a, int b, int st, float (*t)[65]) {
  const float* in; u16* out; int ld, k0, K, Nv, kT;
  int bb = b;
  if (bb < 1024)      {            in = a.W1; out = a.W1nv_t; ld = 2048; k0 = 0;    K = 2048; Nv = 2048; kT = 32; }
  else if (bb < 1536) { bb -= 1024; in = a.W1; out = a.W1v_t;  ld = 2048; k0 = 2048; K = 1024; Nv = 2048; kT = 16; }
  else if (bb < 2048) { bb -= 1536; in = a.W2; out = a.W2t;   ld = 1024; k0 = 0;    K = 2048; Nv = 1024; kT = 32; }
  else if (bb < 2816) { bb -= 2048; in = a.Wk; out = a.Wkt;   ld = 3072; k0 = 0;    K = 1024; Nv = 3072; kT = 16; }
  else if (bb < 3584) { bb -= 2816; in = a.Uk; out = a.Ukt;   ld = 3072; k0 = 0;    K = 1024; Nv = 3072; kT = 16; }
  else if (bb < 3648) { bb -= 3584; in = a.Ws; out = a.Wsnv_t; ld = 51;  k0 = 0;    K = 2048; Nv = 51;   kT = 32; }
  else                { bb -= 3648; in = a.Ws; out = a.Wsv_t;  ld = 51;  k0 = 2048; K = 1024; Nv = 51;   kT = 16; }
  const int kt = (bb % kT) << 6, nt = (bb / kT) << 6;
  const int tx = st & 63, ty = st >> 6;
#pragma unroll
  for (int i = 0; i < 16; ++i) {
    const int kl = ty + i * 4;
    const int n = nt + tx;
    t[kl][tx] = (n < Nv) ? in[(size_t)(k0 + kt + kl) * ld + n] : 0.f;
  }
  __syncthreads();
#pragma unroll
  for (int i = 0; i < 16; ++i)
    out[(size_t)(nt + ty + i * 4) * K + kt + tx] = f2bf(t[tx][ty + i * 4]);
}

static __device__ void misc_elem(int i, const MegaArgs& a) {
  if (i < 2097152) a.nonvis_b[i] = f2bf(a.nonvis[i]);
  if (i < 1048576) { a.hf[i] = 0.f; a.hb[i] = 0; }
  if (i < 2048) { float sc = a.g1[i] * rsqrtf(a.v1[i] + 1e-3f); a.scale1[i] = sc; a.shift1[i] = a.be1[i] - a.m1[i] * sc; }
  if (i < 1024) { float sc = a.g2[i] * rsqrtf(a.v2[i] + 1e-3f); a.scale2[i] = sc; a.shift2[i] = a.be2[i] - a.m2[i] * sc; }
  if (i < 128) a.bs_pad[i] = (i < 51) ? a.bs[i] : 0.f;
}

// convT weight packing: even out-pixel p: w[0]*x[p/2-1] + w[2]*x[p/2]; odd: w[1]*x[(p-1)/2]
static __device__ void build_elem(long idx, const MegaArgs& a) {
  const float* w; const float* bin; u16* wp; float* bp; int Si, CI, CO; long base;
  if (idx < 1048576)      { base = 0;       w = a.ct1w; bin = a.ct1b; wp = a.Wp1; bp = a.bp1; Si = 1; CI = 1024; CO = 256; }
  else if (idx < 2097152) { base = 1048576; w = a.ct2w; bin = a.ct2b; wp = a.Wp2; bp = a.bp2; Si = 2; CI = 256;  CO = 64; }
  else if (idx < 3145728) { base = 2097152; w = a.ct3w; bin = a.ct3b; wp = a.Wp3; bp = a.bp3; Si = 4; CI = 64;   CO = 16; }
  else                    { base = 3145728; w = a.ct4w; bin = a.ct4b; wp = a.Wp4; bp = a.bp4; Si = 8; CI = 16;   CO = 1; }
  const long r = idx - base;
  const int n = (int)(r >> 10), k = (int)(r & 1023);
  const int So = Si * 2;
  const int co = n % CO;
  const int pox = (n / CO) % So;
  const int poy = n / (CO * So);
  const int ci = k % CI;
  const int pix = (k / CI) % Si;
  const int piy = k / (CI * Si);
  int wy = -1, wx = -1;
  if (poy & 1) { if (piy == (poy >> 1)) wy = 1; }
  else { if (piy == (poy >> 1)) wy = 2; else if (piy == (poy >> 1) - 1) wy = 0; }
  if (pox & 1) { if (pix == (pox >> 1)) wx = 1; }
  else { if (pix == (pox >> 1)) wx = 2; else if (pix == (pox >> 1) - 1) wx = 0; }
  float v = 0.f;
  if (wy >= 0 && wx >= 0) v = w[((size_t)(wy * 3 + wx) * CI + ci) * CO + co];
  wp[(size_t)n * 1024 + k] = f2bf(v);
  if (k == 0) bp[n] = bin[co];
}

static __device__ void gru_elem(int idx, const MegaArgs& a, int it) {
  const int b = idx >> 10, d = idx & 1023;
  const float* mxb = a.mx + (size_t)b * 3072;
  const float xz = mxb[d], xr = mxb[d + 1024], xh = mxb[d + 2048];
  float iz, ir, ih;
  if (it == 0) { iz = a.br[d]; ir = a.br[d + 1024]; ih = a.br[d + 2048]; }
  else {
    const float* mib = a.mi + (size_t)b * 3072;
    iz = mib[d]; ir = mib[d + 1024]; ih = mib[d + 2048];
  }
  const float zg = 1.f / (1.f + expf(-(xz + iz)));
  const float rg = 1.f / (1.f + expf(-(xr + ir)));
  const float hh = tanhf(xh + rg * ih);
  const float hn = zg * a.hf[idx] + (1.f - zg) * hh;
  a.hf[idx] = hn;
  a.hb[idx] = f2bf(hn);
}

static __device__ __forceinline__ void taps(int o, int& si, float* w) {
  const float s = 1.6f * (float)o + 0.3f;
  int s0 = (int)ceilf(s - 1.6f);
  if (s0 < 0) s0 = 0;
  si = s0;
  float sum = 0.f;
#pragma unroll
  for (int j = 0; j < 4; ++j) {
    const int i = s0 + j;
    float ww = 0.f;
    if (i <= 15) {
      const float d = fabsf(s - (float)i) * (1.0f / 1.6f);
      ww = fmaxf(0.f, 1.f - d);
    }
    w[j] = ww;
    sum += ww;
  }
  const float inv = 1.f / sum;
#pragma unroll
  for (int j = 0; j < 4; ++j) w[j] *= inv;
}

// -------- fused: bilinear+softmax for this block's 2 batches, then wsum ------
static __device__ void attn_wsum_phase(const MegaArgs& a, char* arena) {
  float* sm = (float*)arena;              // 512 floats
  float* at = (float*)(arena + 2048);     // 2 x 128 floats
  const int tid = threadIdx.x;
  const int sub = tid >> 8, st = tid & 255;
  const int b = (int)blockIdx.x * 2 + sub;
  float val = -1e30f;
  if (st < 100) {
    const int oy = st / 10, ox = st - oy * 10;
    int siy, six;
    float wy[4], wx[4];
    taps(oy, siy, wy);
    taps(ox, six, wx);
    const float* p = a.a4 + (b << 8);
    float s = 0.f;
#pragma unroll
    for (int jy = 0; jy < 4; ++jy) {
      const int iy = min(siy + jy, 15);
      float rs = 0.f;
#pragma unroll
      for (int jx = 0; jx < 4; ++jx) {
        const int ix = min(six + jx, 15);
        rs += wx[jx] * p[(iy << 4) + ix];
      }
      s += wy[jy] * rs;
    }
    val = s;
  }
  sm[tid] = val;
  __syncthreads();
  for (int off = 128; off > 0; off >>= 1) {
    if (st < off) sm[tid] = fmaxf(sm[tid], sm[tid + off]);
    __syncthreads();
  }
  const float mxv = sm[sub << 8];
  __syncthreads();
  const float e = (st < 100) ? expf(val - mxv) : 0.f;
  sm[tid] = e;
  __syncthreads();
  for (int off = 128; off > 0; off >>= 1) {
    if (st < off) sm[tid] += sm[tid + off];
    __syncthreads();
  }
  if (st < 100) at[(sub << 7) + st] = e / sm[sub << 8];
  __syncthreads();
  // ---- wsum for batch b ----
  const int d0 = st << 2;
  float s0 = 0, s1 = 0, s2 = 0, s3 = 0;
  if (a.use_fmb) {
    const u16* p = a.fmb + (size_t)b * 102400 + d0;
    for (int pp = 0; pp < 100; ++pp) {
      const ushort4 v = *(const ushort4*)(p + pp * 1024);
      const float aa = at[(sub << 7) + pp];
      s0 += aa * bf2f(v.x); s1 += aa * bf2f(v.y); s2 += aa * bf2f(v.z); s3 += aa * bf2f(v.w);
    }
  } else {
    const float* p = a.fm + (size_t)b * 102400 + d0;
    for (int pp = 0; pp < 100; ++pp) {
      const float4 v = *(const float4*)(p + pp * 1024);
      const float aa = at[(sub << 7) + pp];
      s0 += aa * v.x; s1 += aa * v.y; s2 += aa * v.z; s3 += aa * v.w;
    }
  }
  const int o = (b << 10) + d0;
  float4 vs = *(float4*)(a.vis_sum + o);
  vs.x += s0; vs.y += s1; vs.z += s2; vs.w += s3;
  *(float4*)(a.vis_sum + o) = vs;
  ushort4 u; u.x = f2bf(s0); u.y = f2bf(s1); u.z = f2bf(s2); u.w = f2bf(s3);
  *(ushort4*)(a.visb + o) = u;
  ushort4 w; w.x = f2bf(vs.x); w.y = f2bf(vs.y); w.z = f2bf(vs.z); w.w = f2bf(vs.w);
  *(ushort4*)(a.vsb + o) = w;
}

// -------- the mega kernel: whole net, one launch --------
__global__ __launch_bounds__(THREADS, 4) void mega_k(MegaArgs a) {
  __shared__ char arena[49152];
  u16* As = (u16*)arena;
  u16* Bs = (u16*)(arena + 16384);
  const int tid = threadIdx.x;
  const int bid = blockIdx.x;
  unsigned ep = 0;

  // ---- PS1: fm_pass + weight transposes + convT packing + misc ----
  for (int j = bid; j < 3024; j += GRID) {
    if (j < 512) {
      const int sub = tid >> 8, st = tid & 255;
      fm_body(a, j * 2 + sub, st);
    } else if (j < 2352) {
      const int sub = tid >> 8, st = tid & 255;
      prep_body(a, (j - 512) * 2 + sub, st, (float(*)[65])(arena + sub * 16640));
    } else if (j < 2608) {
      const int base = (j - 2352) * 8192;
#pragma unroll
      for (int r = 0; r < 16; ++r) misc_elem(base + r * 512 + tid, a);
    } else {
      const long base = (long)(j - 2608) * 8192;
#pragma unroll
      for (int r = 0; r < 16; ++r) build_elem(base + r * 512 + tid, a);
    }
    __syncthreads();
  }
  ++ep; gbar(a.cnt, ep * GRID);

  // ---- PS2: P1 = nonvis@W1nv + b1 (256 tiles); snv = nonvis@Wsnv + bs (16) ----
  for (int j = bid; j < 272; j += GRID) {
    if (j < 256)
      gtile<E_BIAS | E_WF32>(As, Bs, a.nonvis_b, a.W1nv_t, a.P1, nullptr, nullptr,
                             a.b1, nullptr, nullptr, 2048, 2048, j & 15, j >> 4);
    else
      gtile<E_BIAS | E_WF32>(As, Bs, a.nonvis_b, a.Wsnv_t, a.snv, nullptr, nullptr,
                             a.bs_pad, nullptr, nullptr, 128, 2048, 0, j - 256);
  }
  ++ep; gbar(a.cnt, ep * GRID);

  // ---- 5 iterations ----
  for (int it = 0; it < 5; ++it) {
    // PA: x1 = bn(relu(visb@W1v + P1))
    for (int j = bid; j < 256; j += GRID)
      gtile<E_CADD | E_RELU | E_AFF | E_WBF>(As, Bs, a.visb, a.W1v_t, nullptr, a.x1,
                                             a.P1, nullptr, a.scale1, a.shift1,
                                             2048, 1024, j & 15, j >> 4);
    ++ep; gbar(a.cnt, ep * GRID);
    // PB: x2 = bn(relu(x1@W2 + b2))
    for (int j = bid; j < 128; j += GRID)
      gtile<E_BIAS | E_RELU | E_AFF | E_WBF>(As, Bs, a.x1, a.W2t, nullptr, a.x2,
                                             nullptr, a.b2, a.scale2, a.shift2,
                                             1024, 2048, j & 7, j >> 3);
    ++ep; gbar(a.cnt, ep * GRID);
    // PC: mx = x2@Wk + bi
    for (int j = bid; j < 384; j += GRID)
      gtile<E_BIAS | E_WF32>(As, Bs, a.x2, a.Wkt, a.mx, nullptr, nullptr, a.bi,
                             nullptr, nullptr, 3072, 1024, j % 24, j / 24);
    ++ep; gbar(a.cnt, ep * GRID);
    // PD: gru (it==0: mi == br since h==0)
    for (int i = bid * THREADS + tid; i < 1048576; i += GRID * THREADS)
      gru_elem(i, a, it);
    ++ep; gbar(a.cnt, ep * GRID);
    // PE: c1 = relu(hb@Wp1 + bp1); plus mi' = hb@Uk + br for next iter
    {
      const int nj = (it < 4) ? 512 : 128;
      for (int j = bid; j < nj; j += GRID) {
        if (j < 128)
          gtile<E_BIAS | E_RELU | E_WBF>(As, Bs, a.hb, a.Wp1, nullptr, a.a1,
                                         nullptr, a.bp1, nullptr, nullptr,
                                         1024, 1024, j & 7, j >> 3);
        else {
          const int t2 = j - 128;
          gtile<E_BIAS | E_WF32>(As, Bs, a.hb, a.Ukt, a.mi, nullptr, nullptr, a.br,
                                 nullptr, nullptr, 3072, 1024, t2 % 24, t2 / 24);
        }
      }
    }
    ++ep; gbar(a.cnt, ep * GRID);
    // PF: c2
    for (int j = bid; j < 128; j += GRID)
      gtile<E_BIAS | E_RELU | E_WBF>(As, Bs, a.a1, a.Wp2, nullptr, a.a2, nullptr,
                                     a.bp2, nullptr, nullptr, 1024, 1024, j & 7, j >> 3);
    ++ep; gbar(a.cnt, ep * GRID);
    // PG: c3
    for (int j = bid; j < 128; j += GRID)
      gtile<E_BIAS | E_RELU | E_WBF>(As, Bs, a.a2, a.Wp3, nullptr, a.a3, nullptr,
                                     a.bp3, nullptr, nullptr, 1024, 1024, j & 7, j >> 3);
    ++ep; gbar(a.cnt, ep * GRID);
    // PH: c4 -> a4 (1024 x 256 fp32)
    for (int j = bid; j < 32; j += GRID)
      gtile<E_BIAS | E_WF32>(As, Bs, a.a3, a.Wp4, a.a4, nullptr, nullptr, a.bp4,
                             nullptr, nullptr, 256, 1024, j & 1, j >> 1);
    ++ep; gbar(a.cnt, ep * GRID);
    // PIJ: bilinear+softmax (in-LDS) then wsum, same block handles its 2 batches
    attn_wsum_phase(a, arena);
    ++ep; gbar(a.cnt, ep * GRID);
  }

  // PZ: out = (vsb@Wsv)/6 + snv + prior  (fused epilogue)
  for (int j = bid; j < 16; j += GRID)
    gtile<E_FINAL>(As, Bs, a.vsb, a.Wsv_t, a.out, nullptr, a.snv, nullptr,
                   a.prior, nullptr, 128, 1024, 0, j);
}

extern "C" void kernel_launch(void* const* d_in, const int* in_sizes, int n_in,
                              void* d_out, int out_size, void* d_ws, size_t ws_size,
                              hipStream_t stream) {
  (void)in_sizes; (void)n_in; (void)out_size;
  MegaArgs a;
  a.nonvis = (const float*)d_in[0];  a.fm   = (const float*)d_in[1];
  a.prior  = (const float*)d_in[2];  a.W1   = (const float*)d_in[3];
  a.b1  = (const float*)d_in[4];     a.g1   = (const float*)d_in[5];
  a.be1 = (const float*)d_in[6];     a.m1   = (const float*)d_in[7];
  a.v1  = (const float*)d_in[8];     a.W2   = (const float*)d_in[9];
  a.b2  = (const float*)d_in[10];    a.g2   = (const float*)d_in[11];
  a.be2 = (const float*)d_in[12];    a.m2   = (const float*)d_in[13];
  a.v2  = (const float*)d_in[14];    a.Wk   = (const float*)d_in[15];
  a.Uk  = (const float*)d_in[16];    a.bi   = (const float*)d_in[17];
  a.br  = (const float*)d_in[18];    a.ct1w = (const float*)d_in[19];
  a.ct1b = (const float*)d_in[20];   a.ct2w = (const float*)d_in[21];
  a.ct2b = (const float*)d_in[22];   a.ct3w = (const float*)d_in[23];
  a.ct3b = (const float*)d_in[24];   a.ct4w = (const float*)d_in[25];
  a.ct4b = (const float*)d_in[26];   a.Ws   = (const float*)d_in[27];
  a.bs  = (const float*)d_in[28];

  char* base = (char*)d_ws;
  size_t off = 0;
  auto alloc = [&](size_t bytes) -> void* {
    void* r = base + off;
    off = (off + bytes + 255) & ~(size_t)255;
    return r;
  };

  a.cnt      = (unsigned*)alloc(256);
  a.nonvis_b = (u16*)alloc(4194304);
  a.W1nv_t   = (u16*)alloc(8388608);
  a.W1v_t    = (u16*)alloc(4194304);
  a.W2t      = (u16*)alloc(4194304);
  a.Wkt      = (u16*)alloc(6291456);
  a.Ukt      = (u16*)alloc(6291456);
  a.Wsnv_t   = (u16*)alloc(524288);
  a.Wsv_t    = (u16*)alloc(262144);
  a.Wp1      = (u16*)alloc(2097152);
  a.Wp2      = (u16*)alloc(2097152);
  a.Wp3      = (u16*)alloc(2097152);
  a.Wp4      = (u16*)alloc(524288);
  a.bp1      = (float*)alloc(4096);
  a.bp2      = (float*)alloc(4096);
  a.bp3      = (float*)alloc(4096);
  a.bp4      = (float*)alloc(1024);
  a.scale1   = (float*)alloc(8192);
  a.shift1   = (float*)alloc(8192);
  a.scale2   = (float*)alloc(4096);
  a.shift2   = (float*)alloc(4096);
  a.bs_pad   = (float*)alloc(512);
  a.P1       = (float*)alloc(8388608);
  a.snv      = (float*)alloc(524288);
  a.x1       = (u16*)alloc(4194304);
  a.x2       = (u16*)alloc(2097152);
  a.mx       = (float*)alloc(12582912);
  a.mi       = (float*)alloc(12582912);
  a.hf       = (float*)alloc(4194304);
  a.hb       = (u16*)alloc(2097152);
  a.a1       = (u16*)alloc(2097152);
  a.a2       = (u16*)alloc(2097152);
  a.a3       = (u16*)alloc(2097152);
  a.a4       = (float*)alloc(1048576);
  a.vis_sum  = (float*)alloc(4194304);
  a.visb     = (u16*)alloc(2097152);
  a.vsb      = (u16*)alloc(2097152);
  a.out      = (float*)d_out;
  a.fmb = nullptr;
  a.use_fmb = 0;
  if (off + (size_t)209715200 + 256 <= ws_size) {
    a.fmb = (u16*)alloc(209715200);
    a.use_fmb = 1;
  }

  hipMemsetAsync(a.cnt, 0, 8, stream);
  mega_k<<<GRID, THREADS, 0, stream>>>(a);
}

// Round 6
// 2092.212 us; speedup vs baseline: 2.9860x; 2.9860x over previous
//
#include <hip/hip_runtime.h>

typedef unsigned short u16;
typedef __attribute__((ext_vector_type(8))) __bf16 bf16x8;
typedef __attribute__((ext_vector_type(4))) float f32x4;

typedef __attribute__((address_space(1))) const void gvoid_t;
typedef __attribute__((address_space(3))) void lvoid_t;

enum { E_CADD = 1, E_BIAS = 2, E_RELU = 4, E_AFF = 8, E_WBF = 16, E_WF32 = 32, E_FINAL = 64 };

#define GRID 256
#define THREADS 512

static __device__ __forceinline__ u16 f2bf(float f) {
  unsigned u = __float_as_uint(f);
  u += 0x7fffu + ((u >> 16) & 1u);
  return (u16)(u >> 16);
}
static __device__ __forceinline__ float bf2f(u16 h) {
  return __uint_as_float(((unsigned)h) << 16);
}

struct MegaArgs {
  const float *nonvis, *fm, *prior, *W1, *b1, *g1, *be1, *m1, *v1;
  const float *W2, *b2, *g2, *be2, *m2, *v2, *Wk, *Uk, *bi, *br;
  const float *ct1w, *ct1b, *ct2w, *ct2b, *ct3w, *ct3b, *ct4w, *ct4b, *Ws, *bs;
  u16 *nonvis_b, *W1nv_t, *W1v_t, *W2t, *Wkt, *Ukt, *Wsnv_t, *Wsv_t;
  u16 *Wp1, *Wp2, *Wp3, *Wp4;
  float *bp1, *bp2, *bp3, *bp4, *scale1, *shift1, *scale2, *shift2, *bs_pad;
  float *P1, *snv, *mx, *mi, *hf;
  u16 *x1, *x2, *hb, *a1, *a2, *a3;
  float *a4, *vis_sum;
  u16 *visb, *vsb, *fmb;
  float *out;
  unsigned *cnt;
  int use_fmb;
};

// ---- device-scope grid barrier --------------------------------------------
// release fetch_add (one L2 wb) -> RELAXED spin (plain sc1 load, NO per-poll
// cache op -- R5's bug was an ACQUIRE load in the loop = buffer_inv per poll,
// wiping every XCD's L2 continuously) -> ONE acquire load after exit.
static __device__ __forceinline__ void gbar(unsigned* cnt, unsigned goal) {
  __syncthreads();
  if (threadIdx.x == 0) {
    __hip_atomic_fetch_add(cnt, 1u, __ATOMIC_RELEASE, __HIP_MEMORY_SCOPE_AGENT);
    while (__hip_atomic_load(cnt, __ATOMIC_RELAXED, __HIP_MEMORY_SCOPE_AGENT) < goal)
      __builtin_amdgcn_s_sleep(2);
    (void)__hip_atomic_load(cnt, __ATOMIC_ACQUIRE, __HIP_MEMORY_SCOPE_AGENT);
  }
  __syncthreads();
}

// -------- 64x128 MFMA GEMM tile, 8 waves, dbuf LDS + XOR swizzle (T2) --------
template <int FLAGS>
static __device__ void gtile(u16* As, u16* Bs,
    const u16* __restrict__ A, const u16* __restrict__ Bt,
    float* __restrict__ Cf, u16* __restrict__ Cb,
    const float* __restrict__ Cadd, const float* __restrict__ bias,
    const float* __restrict__ scale, const float* __restrict__ shift,
    int N, int K, int bx, int by) {
  const int tid = threadIdx.x;
  const int wave = tid >> 6, lane = tid & 63;
  const int bm = by << 6, bn = bx << 7;
  const int lr = lane & 15, lg = lane >> 4;
  const int rx = lr & 7;
  const int wm = (wave >> 2) << 5, wn = (wave & 3) << 5;

  f32x4 acc[2][2] = {};

  auto stage = [&](int buf, int kt) {
    { const int row = tid >> 3;
      const int cg = (tid & 7) ^ (row & 7);
      __builtin_amdgcn_global_load_lds(
          (gvoid_t*)(A + (size_t)(bm + row) * K + kt + (cg << 3)),
          (lvoid_t*)(As + buf * 4096 + wave * 512), 16, 0, 0); }
#pragma unroll
    for (int i = 0; i < 2; ++i) {
      const int li = i * 512 + tid;
      const int row = li >> 3;
      const int cg = (li & 7) ^ (row & 7);
      __builtin_amdgcn_global_load_lds(
          (gvoid_t*)(Bt + (size_t)(bn + row) * K + kt + (cg << 3)),
          (lvoid_t*)(Bs + buf * 8192 + i * 4096 + wave * 512), 16, 0, 0);
    }
  };

  stage(0, 0);
  int buf = 0;
  for (int kt = 0; kt < K; kt += 64) {
    __syncthreads();                       // buf staged; prev reads done
    if (kt + 64 < K) stage(buf ^ 1, kt + 64);
    const u16* Ab = As + buf * 4096;
    const u16* Bb = Bs + buf * 8192;
#pragma unroll
    for (int kk = 0; kk < 64; kk += 32) {
      bf16x8 av[2], bv[2];
#pragma unroll
      for (int mi2 = 0; mi2 < 2; ++mi2)
        av[mi2] = *(const bf16x8*)(Ab + ((wm + mi2 * 16 + lr) << 6) +
                                   ((((kk >> 3) + lg) ^ rx) << 3));
#pragma unroll
      for (int ni = 0; ni < 2; ++ni)
        bv[ni] = *(const bf16x8*)(Bb + ((wn + ni * 16 + lr) << 6) +
                                  ((((kk >> 3) + lg) ^ rx) << 3));
#pragma unroll
      for (int mi2 = 0; mi2 < 2; ++mi2)
#pragma unroll
        for (int ni = 0; ni < 2; ++ni)
          acc[mi2][ni] = __builtin_amdgcn_mfma_f32_16x16x32_bf16(av[mi2], bv[ni], acc[mi2][ni], 0, 0, 0);
    }
    buf ^= 1;
  }

#pragma unroll
  for (int mi2 = 0; mi2 < 2; ++mi2) {
#pragma unroll
    for (int ni = 0; ni < 2; ++ni) {
      const int col = bn + wn + ni * 16 + lr;
#pragma unroll
      for (int r = 0; r < 4; ++r) {
        const int row = bm + wm + mi2 * 16 + (lg << 2) + r;
        float v = acc[mi2][ni][r];
        if (FLAGS & E_FINAL) {
          if (col < 51)
            Cf[row * 51 + col] = v * (1.f / 6.f) + Cadd[(row << 7) + col] + scale[row * 51 + col];
        } else {
          if (FLAGS & E_CADD) v += Cadd[(size_t)row * N + col];
          if (FLAGS & E_BIAS) v += bias[col];
          if (FLAGS & E_RELU) v = fmaxf(v, 0.f);
          if (FLAGS & E_AFF) v = v * scale[col] + shift[col];
          if (FLAGS & E_WF32) Cf[(size_t)row * N + col] = v;
          if (FLAGS & E_WBF) Cb[(size_t)row * N + col] = f2bf(v);
        }
      }
    }
  }
  __syncthreads();                         // protect LDS reuse by next job
}

// -------- phase bodies --------
static __device__ void fm_body(const MegaArgs& a, int b, int st) {
  const int d0 = st << 2;
  const float* p = a.fm + (size_t)b * 102400 + d0;
  float s0 = 0, s1 = 0, s2 = 0, s3 = 0;
  for (int pp = 0; pp < 100; ++pp) {
    const float4 v = *(const float4*)(p + pp * 1024);
    if (a.use_fmb) {
      ushort4 u;
      u.x = f2bf(v.x); u.y = f2bf(v.y); u.z = f2bf(v.z); u.w = f2bf(v.w);
      *(ushort4*)(a.fmb + (size_t)b * 102400 + pp * 1024 + d0) = u;
    }
    s0 += v.x; s1 += v.y; s2 += v.z; s3 += v.w;
  }
  const float inv = 1.0f / 100.0f;
  s0 *= inv; s1 *= inv; s2 *= inv; s3 *= inv;
  const int o = (b << 10) + d0;
  float4 m; m.x = s0; m.y = s1; m.z = s2; m.w = s3;
  *(float4*)(a.vis_sum + o) = m;
  ushort4 u; u.x = f2bf(s0); u.y = f2bf(s1); u.z = f2bf(s2); u.w = f2bf(s3);
  *(ushort4*)(a.visb + o) = u;
}

static __device__ void prep_body(const MegaArgs& a, int b, int st, float (*t)[65]) {
  const float* in; u16* out; int ld, k0, K, Nv, kT;
  int bb = b;
  if (bb < 1024)      {            in = a.W1; out = a.W1nv_t; ld = 2048; k0 = 0;    K = 2048; Nv = 2048; kT = 32; }
  else if (bb < 1536) { bb -= 1024; in = a.W1; out = a.W1v_t;  ld = 2048; k0 = 2048; K = 1024; Nv = 2048; kT = 16; }
  else if (bb < 2048) { bb -= 1536; in = a.W2; out = a.W2t;   ld = 1024; k0 = 0;    K = 2048; Nv = 1024; kT = 32; }
  else if (bb < 2816) { bb -= 2048; in = a.Wk; out = a.Wkt;   ld = 3072; k0 = 0;    K = 1024; Nv = 3072; kT = 16; }
  else if (bb < 3584) { bb -= 2816; in = a.Uk; out = a.Ukt;   ld = 3072; k0 = 0;    K = 1024; Nv = 3072; kT = 16; }
  else if (bb < 3648) { bb -= 3584; in = a.Ws; out = a.Wsnv_t; ld = 51;  k0 = 0;    K = 2048; Nv = 51;   kT = 32; }
  else                { bb -= 3648; in = a.Ws; out = a.Wsv_t;  ld = 51;  k0 = 2048; K = 1024; Nv = 51;   kT = 16; }
  const int kt = (bb % kT) << 6, nt = (bb / kT) << 6;
  const int tx = st & 63, ty = st >> 6;
#pragma unroll
  for (int i = 0; i < 16; ++i) {
    const int kl = ty + i * 4;
    const int n = nt + tx;
    t[kl][tx] = (n < Nv) ? in[(size_t)(k0 + kt + kl) * ld + n] : 0.f;
  }
  __syncthreads();
#pragma unroll
  for (int i = 0; i < 16; ++i)
    out[(size_t)(nt + ty + i * 4) * K + kt + tx] = f2bf(t[tx][ty + i * 4]);
}

static __device__ void misc_elem(int i, const MegaArgs& a) {
  if (i < 2097152) a.nonvis_b[i] = f2bf(a.nonvis[i]);
  if (i < 1048576) { a.hf[i] = 0.f; a.hb[i] = 0; }
  if (i < 2048) { float sc = a.g1[i] * rsqrtf(a.v1[i] + 1e-3f); a.scale1[i] = sc; a.shift1[i] = a.be1[i] - a.m1[i] * sc; }
  if (i < 1024) { float sc = a.g2[i] * rsqrtf(a.v2[i] + 1e-3f); a.scale2[i] = sc; a.shift2[i] = a.be2[i] - a.m2[i] * sc; }
  if (i < 128) a.bs_pad[i] = (i < 51) ? a.bs[i] : 0.f;
}

// convT weight packing: even out-pixel p: w[0]*x[p/2-1] + w[2]*x[p/2]; odd: w[1]*x[(p-1)/2]
static __device__ void build_elem(long idx, const MegaArgs& a) {
  const float* w; const float* bin; u16* wp; float* bp; int Si, CI, CO; long base;
  if (idx < 1048576)      { base = 0;       w = a.ct1w; bin = a.ct1b; wp = a.Wp1; bp = a.bp1; Si = 1; CI = 1024; CO = 256; }
  else if (idx < 2097152) { base = 1048576; w = a.ct2w; bin = a.ct2b; wp = a.Wp2; bp = a.bp2; Si = 2; CI = 256;  CO = 64; }
  else if (idx < 3145728) { base = 2097152; w = a.ct3w; bin = a.ct3b; wp = a.Wp3; bp = a.bp3; Si = 4; CI = 64;   CO = 16; }
  else                    { base = 3145728; w = a.ct4w; bin = a.ct4b; wp = a.Wp4; bp = a.bp4; Si = 8; CI = 16;   CO = 1; }
  const long r = idx - base;
  const int n = (int)(r >> 10), k = (int)(r & 1023);
  const int So = Si * 2;
  const int co = n % CO;
  const int pox = (n / CO) % So;
  const int poy = n / (CO * So);
  const int ci = k % CI;
  const int pix = (k / CI) % Si;
  const int piy = k / (CI * Si);
  int wy = -1, wx = -1;
  if (poy & 1) { if (piy == (poy >> 1)) wy = 1; }
  else { if (piy == (poy >> 1)) wy = 2; else if (piy == (poy >> 1) - 1) wy = 0; }
  if (pox & 1) { if (pix == (pox >> 1)) wx = 1; }
  else { if (pix == (pox >> 1)) wx = 2; else if (pix == (pox >> 1) - 1) wx = 0; }
  float v = 0.f;
  if (wy >= 0 && wx >= 0) v = w[((size_t)(wy * 3 + wx) * CI + ci) * CO + co];
  wp[(size_t)n * 1024 + k] = f2bf(v);
  if (k == 0) bp[n] = bin[co];
}

static __device__ void gru_elem(int idx, const MegaArgs& a, int it) {
  const int b = idx >> 10, d = idx & 1023;
  const float* mxb = a.mx + (size_t)b * 3072;
  const float xz = mxb[d], xr = mxb[d + 1024], xh = mxb[d + 2048];
  float iz, ir, ih;
  if (it == 0) { iz = a.br[d]; ir = a.br[d + 1024]; ih = a.br[d + 2048]; }
  else {
    const float* mib = a.mi + (size_t)b * 3072;
    iz = mib[d]; ir = mib[d + 1024]; ih = mib[d + 2048];
  }
  const float zg = 1.f / (1.f + expf(-(xz + iz)));
  const float rg = 1.f / (1.f + expf(-(xr + ir)));
  const float hh = tanhf(xh + rg * ih);
  const float hn = zg * a.hf[idx] + (1.f - zg) * hh;
  a.hf[idx] = hn;
  a.hb[idx] = f2bf(hn);
}

static __device__ __forceinline__ void taps(int o, int& si, float* w) {
  const float s = 1.6f * (float)o + 0.3f;
  int s0 = (int)ceilf(s - 1.6f);
  if (s0 < 0) s0 = 0;
  si = s0;
  float sum = 0.f;
#pragma unroll
  for (int j = 0; j < 4; ++j) {
    const int i = s0 + j;
    float ww = 0.f;
    if (i <= 15) {
      const float d = fabsf(s - (float)i) * (1.0f / 1.6f);
      ww = fmaxf(0.f, 1.f - d);
    }
    w[j] = ww;
    sum += ww;
  }
  const float inv = 1.f / sum;
#pragma unroll
  for (int j = 0; j < 4; ++j) w[j] *= inv;
}

// -------- fused: bilinear+softmax for job j's 2 batches, then wsum -----------
static __device__ void attn_wsum_job(const MegaArgs& a, int j, char* arena) {
  float* sm = (float*)arena;              // 512 floats
  float* at = (float*)(arena + 2048);     // 2 x 128 floats
  const int tid = threadIdx.x;
  const int sub = tid >> 8, st = tid & 255;
  const int b = j * 2 + sub;
  float val = -1e30f;
  if (st < 100) {
    const int oy = st / 10, ox = st - oy * 10;
    int siy, six;
    float wy[4], wx[4];
    taps(oy, siy, wy);
    taps(ox, six, wx);
    const float* p = a.a4 + (b << 8);
    float s = 0.f;
#pragma unroll
    for (int jy = 0; jy < 4; ++jy) {
      const int iy = min(siy + jy, 15);
      float rs = 0.f;
#pragma unroll
      for (int jx = 0; jx < 4; ++jx) {
        const int ix = min(six + jx, 15);
        rs += wx[jx] * p[(iy << 4) + ix];
      }
      s += wy[jy] * rs;
    }
    val = s;
  }
  sm[tid] = val;
  __syncthreads();
  for (int off = 128; off > 0; off >>= 1) {
    if (st < off) sm[tid] = fmaxf(sm[tid], sm[tid + off]);
    __syncthreads();
  }
  const float mxv = sm[sub << 8];
  __syncthreads();
  const float e = (st < 100) ? expf(val - mxv) : 0.f;
  sm[tid] = e;
  __syncthreads();
  for (int off = 128; off > 0; off >>= 1) {
    if (st < off) sm[tid] += sm[tid + off];
    __syncthreads();
  }
  if (st < 100) at[(sub << 7) + st] = e / sm[sub << 8];
  __syncthreads();
  // ---- wsum for batch b ----
  const int d0 = st << 2;
  float s0 = 0, s1 = 0, s2 = 0, s3 = 0;
  if (a.use_fmb) {
    const u16* p = a.fmb + (size_t)b * 102400 + d0;
    for (int pp = 0; pp < 100; ++pp) {
      const ushort4 v = *(const ushort4*)(p + pp * 1024);
      const float aa = at[(sub << 7) + pp];
      s0 += aa * bf2f(v.x); s1 += aa * bf2f(v.y); s2 += aa * bf2f(v.z); s3 += aa * bf2f(v.w);
    }
  } else {
    const float* p = a.fm + (size_t)b * 102400 + d0;
    for (int pp = 0; pp < 100; ++pp) {
      const float4 v = *(const float4*)(p + pp * 1024);
      const float aa = at[(sub << 7) + pp];
      s0 += aa * v.x; s1 += aa * v.y; s2 += aa * v.z; s3 += aa * v.w;
    }
  }
  const int o = (b << 10) + d0;
  float4 vs = *(float4*)(a.vis_sum + o);
  vs.x += s0; vs.y += s1; vs.z += s2; vs.w += s3;
  *(float4*)(a.vis_sum + o) = vs;
  ushort4 u; u.x = f2bf(s0); u.y = f2bf(s1); u.z = f2bf(s2); u.w = f2bf(s3);
  *(ushort4*)(a.visb + o) = u;
  ushort4 w; w.x = f2bf(vs.x); w.y = f2bf(vs.y); w.z = f2bf(vs.z); w.w = f2bf(vs.w);
  *(ushort4*)(a.vsb + o) = w;
}

// -------- the mega kernel: whole net, one launch --------
__global__ __launch_bounds__(THREADS) void mega_k(MegaArgs a) {
  __shared__ char arena[49152];
  u16* As = (u16*)arena;
  u16* Bs = (u16*)(arena + 16384);
  const int tid = threadIdx.x;
  const int bid = blockIdx.x;
  unsigned ep = 0;

  // ---- PS1: fm_pass + weight transposes + convT packing + misc ----
  for (int j = bid; j < 3024; j += GRID) {
    if (j < 512) {
      const int sub = tid >> 8, st = tid & 255;
      fm_body(a, j * 2 + sub, st);
    } else if (j < 2352) {
      const int sub = tid >> 8, st = tid & 255;
      prep_body(a, (j - 512) * 2 + sub, st, (float(*)[65])(arena + sub * 16640));
    } else if (j < 2608) {
      const int base = (j - 2352) * 8192;
#pragma unroll
      for (int r = 0; r < 16; ++r) misc_elem(base + r * 512 + tid, a);
    } else {
      const long base = (long)(j - 2608) * 8192;
#pragma unroll
      for (int r = 0; r < 16; ++r) build_elem(base + r * 512 + tid, a);
    }
    __syncthreads();
  }
  ++ep; gbar(a.cnt, ep * GRID);

  // ---- PS2: P1 = nonvis@W1nv + b1 (256 tiles); snv = nonvis@Wsnv + bs (16) ----
  for (int j = bid; j < 272; j += GRID) {
    if (j < 256)
      gtile<E_BIAS | E_WF32>(As, Bs, a.nonvis_b, a.W1nv_t, a.P1, nullptr, nullptr,
                             a.b1, nullptr, nullptr, 2048, 2048, j & 15, j >> 4);
    else
      gtile<E_BIAS | E_WF32>(As, Bs, a.nonvis_b, a.Wsnv_t, a.snv, nullptr, nullptr,
                             a.bs_pad, nullptr, nullptr, 128, 2048, 0, j - 256);
  }
  ++ep; gbar(a.cnt, ep * GRID);

  // ---- 5 iterations ----
  for (int it = 0; it < 5; ++it) {
    // PA: x1 = bn(relu(visb@W1v + P1))
    for (int j = bid; j < 256; j += GRID)
      gtile<E_CADD | E_RELU | E_AFF | E_WBF>(As, Bs, a.visb, a.W1v_t, nullptr, a.x1,
                                             a.P1, nullptr, a.scale1, a.shift1,
                                             2048, 1024, j & 15, j >> 4);
    ++ep; gbar(a.cnt, ep * GRID);
    // PB: x2 = bn(relu(x1@W2 + b2))
    for (int j = bid; j < 128; j += GRID)
      gtile<E_BIAS | E_RELU | E_AFF | E_WBF>(As, Bs, a.x1, a.W2t, nullptr, a.x2,
                                             nullptr, a.b2, a.scale2, a.shift2,
                                             1024, 2048, j & 7, j >> 3);
    ++ep; gbar(a.cnt, ep * GRID);
    // PC: mx = x2@Wk + bi
    for (int j = bid; j < 384; j += GRID)
      gtile<E_BIAS | E_WF32>(As, Bs, a.x2, a.Wkt, a.mx, nullptr, nullptr, a.bi,
                             nullptr, nullptr, 3072, 1024, j % 24, j / 24);
    ++ep; gbar(a.cnt, ep * GRID);
    // PD: gru (it==0: mi == br since h==0)
    for (int i = bid * THREADS + tid; i < 1048576; i += GRID * THREADS)
      gru_elem(i, a, it);
    ++ep; gbar(a.cnt, ep * GRID);
    // PE: c1 = relu(hb@Wp1 + bp1); plus mi' = hb@Uk + br for next iter
    {
      const int nj = (it < 4) ? 512 : 128;
      for (int j = bid; j < nj; j += GRID) {
        if (j < 128)
          gtile<E_BIAS | E_RELU | E_WBF>(As, Bs, a.hb, a.Wp1, nullptr, a.a1,
                                         nullptr, a.bp1, nullptr, nullptr,
                                         1024, 1024, j & 7, j >> 3);
        else {
          const int t2 = j - 128;
          gtile<E_BIAS | E_WF32>(As, Bs, a.hb, a.Ukt, a.mi, nullptr, nullptr, a.br,
                                 nullptr, nullptr, 3072, 1024, t2 % 24, t2 / 24);
        }
      }
    }
    ++ep; gbar(a.cnt, ep * GRID);
    // PF: c2
    for (int j = bid; j < 128; j += GRID)
      gtile<E_BIAS | E_RELU | E_WBF>(As, Bs, a.a1, a.Wp2, nullptr, a.a2, nullptr,
                                     a.bp2, nullptr, nullptr, 1024, 1024, j & 7, j >> 3);
    ++ep; gbar(a.cnt, ep * GRID);
    // PG: c3
    for (int j = bid; j < 128; j += GRID)
      gtile<E_BIAS | E_RELU | E_WBF>(As, Bs, a.a2, a.Wp3, nullptr, a.a3, nullptr,
                                     a.bp3, nullptr, nullptr, 1024, 1024, j & 7, j >> 3);
    ++ep; gbar(a.cnt, ep * GRID);
    // PH: c4 -> a4 (1024 x 256 fp32)
    for (int j = bid; j < 32; j += GRID)
      gtile<E_BIAS | E_WF32>(As, Bs, a.a3, a.Wp4, a.a4, nullptr, nullptr, a.bp4,
                             nullptr, nullptr, 256, 1024, j & 1, j >> 1);
    ++ep; gbar(a.cnt, ep * GRID);
    // PIJ: bilinear+softmax (in-LDS) then wsum; 512 jobs x 2 batches
    for (int j = bid; j < 512; j += GRID)
      attn_wsum_job(a, j, arena);
    ++ep; gbar(a.cnt, ep * GRID);
  }

  // PZ: out = (vsb@Wsv)/6 + snv + prior  (fused epilogue)
  for (int j = bid; j < 16; j += GRID)
    gtile<E_FINAL>(As, Bs, a.vsb, a.Wsv_t, a.out, nullptr, a.snv, nullptr,
                   a.prior, nullptr, 128, 1024, 0, j);
}

extern "C" void kernel_launch(void* const* d_in, const int* in_sizes, int n_in,
                              void* d_out, int out_size, void* d_ws, size_t ws_size,
                              hipStream_t stream) {
  (void)in_sizes; (void)n_in; (void)out_size;
  MegaArgs a;
  a.nonvis = (const float*)d_in[0];  a.fm   = (const float*)d_in[1];
  a.prior  = (const float*)d_in[2];  a.W1   = (const float*)d_in[3];
  a.b1  = (const float*)d_in[4];     a.g1   = (const float*)d_in[5];
  a.be1 = (const float*)d_in[6];     a.m1   = (const float*)d_in[7];
  a.v1  = (const float*)d_in[8];     a.W2   = (const float*)d_in[9];
  a.b2  = (const float*)d_in[10];    a.g2   = (const float*)d_in[11];
  a.be2 = (const float*)d_in[12];    a.m2   = (const float*)d_in[13];
  a.v2  = (const float*)d_in[14];    a.Wk   = (const float*)d_in[15];
  a.Uk  = (const float*)d_in[16];    a.bi   = (const float*)d_in[17];
  a.br  = (const float*)d_in[18];    a.ct1w = (const float*)d_in[19];
  a.ct1b = (const float*)d_in[20];   a.ct2w = (const float*)d_in[21];
  a.ct2b = (const float*)d_in[22];   a.ct3w = (const float*)d_in[23];
  a.ct3b = (const float*)d_in[24];   a.ct4w = (const float*)d_in[25];
  a.ct4b = (const float*)d_in[26];   a.Ws   = (const float*)d_in[27];
  a.bs  = (const float*)d_in[28];

  char* base = (char*)d_ws;
  size_t off = 0;
  auto alloc = [&](size_t bytes) -> void* {
    void* r = base + off;
    off = (off + bytes + 255) & ~(size_t)255;
    return r;
  };

  a.cnt      = (unsigned*)alloc(256);
  a.nonvis_b = (u16*)alloc(4194304);
  a.W1nv_t   = (u16*)alloc(8388608);
  a.W1v_t    = (u16*)alloc(4194304);
  a.W2t      = (u16*)alloc(4194304);
  a.Wkt      = (u16*)alloc(6291456);
  a.Ukt      = (u16*)alloc(6291456);
  a.Wsnv_t   = (u16*)alloc(524288);
  a.Wsv_t    = (u16*)alloc(262144);
  a.Wp1      = (u16*)alloc(2097152);
  a.Wp2      = (u16*)alloc(2097152);
  a.Wp3      = (u16*)alloc(2097152);
  a.Wp4      = (u16*)alloc(524288);
  a.bp1      = (float*)alloc(4096);
  a.bp2      = (float*)alloc(4096);
  a.bp3      = (float*)alloc(4096);
  a.bp4      = (float*)alloc(1024);
  a.scale1   = (float*)alloc(8192);
  a.shift1   = (float*)alloc(8192);
  a.scale2   = (float*)alloc(4096);
  a.shift2   = (float*)alloc(4096);
  a.bs_pad   = (float*)alloc(512);
  a.P1       = (float*)alloc(8388608);
  a.snv      = (float*)alloc(524288);
  a.x1       = (u16*)alloc(4194304);
  a.x2       = (u16*)alloc(2097152);
  a.mx       = (float*)alloc(12582912);
  a.mi       = (float*)alloc(12582912);
  a.hf       = (float*)alloc(4194304);
  a.hb       = (u16*)alloc(2097152);
  a.a1       = (u16*)alloc(2097152);
  a.a2       = (u16*)alloc(2097152);
  a.a3       = (u16*)alloc(2097152);
  a.a4       = (float*)alloc(1048576);
  a.vis_sum  = (float*)alloc(4194304);
  a.visb     = (u16*)alloc(2097152);
  a.vsb      = (u16*)alloc(2097152);
  a.out      = (float*)d_out;
  a.fmb = nullptr;
  a.use_fmb = 0;
  if (off + (size_t)209715200 + 256 <= ws_size) {
    a.fmb = (u16*)alloc(209715200);
    a.use_fmb = 1;
  }

  hipMemsetAsync(a.cnt, 0, 8, stream);
  mega_k<<<GRID, THREADS, 0, stream>>>(a);
}

// Round 7
// 1696.421 us; speedup vs baseline: 3.6826x; 1.2333x over previous
//
#include <hip/hip_runtime.h>

typedef unsigned short u16;
typedef __attribute__((ext_vector_type(8))) __bf16 bf16x8;
typedef __attribute__((ext_vector_type(4))) float f32x4;

typedef __attribute__((address_space(1))) const void gvoid_t;
typedef __attribute__((address_space(3))) void lvoid_t;

enum { E_CADD = 1, E_BIAS = 2, E_RELU = 4, E_AFF = 8, E_WBF = 16, E_WF32 = 32, E_FINAL = 64 };

#define GRID 256
#define THREADS 512

static __device__ __forceinline__ u16 f2bf(float f) {
  unsigned u = __float_as_uint(f);
  u += 0x7fffu + ((u >> 16) & 1u);
  return (u16)(u >> 16);
}
static __device__ __forceinline__ float bf2f(u16 h) {
  return __uint_as_float(((unsigned)h) << 16);
}

struct MegaArgs {
  const float *nonvis, *fm, *prior, *W1, *b1, *g1, *be1, *m1, *v1;
  const float *W2, *b2, *g2, *be2, *m2, *v2, *Wk, *Uk, *bi, *br;
  const float *ct1w, *ct1b, *ct2w, *ct2b, *ct3w, *ct3b, *ct4w, *ct4b, *Ws, *bs;
  u16 *nonvis_b, *W1nv_t, *W1v_t, *W2t, *Wkt, *Ukt, *Wsnv_t, *Wsv_t;
  u16 *Wp1, *Wp2, *Wp3, *Wp4;
  float *bp1, *bp2, *bp3, *bp4, *scale1, *shift1, *scale2, *shift2, *bs_pad;
  float *P1, *snv, *mx, *mi, *hf;
  u16 *x1, *x2, *hb, *a1, *a2, *a3;
  float *a4, *vis_sum;
  u16 *visb, *vsb, *fmb;
  float *out;
  unsigned *ctrl;
  int use_fmb;
};

// ---- two-level device-scope grid barrier ----------------------------------
// Every block: RELEASE fetch_add on its group line (flushes its OWN physical
// XCD L2 -> correctness independent of grouping; 32 contenders/line).
// Group leader (32nd arrival): relaxed add + poll on global line (8 pollers
// only), one acquire-inv, open group gate. Followers: relaxed poll of gate
// line + one acquire-inv. All polls relaxed (no per-poll cache ops).
static __device__ __forceinline__ void gbar2(unsigned* ctrl, int grp, int ep) {
  __syncthreads();
  if (threadIdx.x == 0) {
    unsigned* xc = ctrl + 32 + 32 * grp;   // group arrival counter (128B apart)
    unsigned* xf = ctrl + 320 + 32 * grp;  // group gate
    const unsigned old =
        __hip_atomic_fetch_add(xc, 1u, __ATOMIC_RELEASE, __HIP_MEMORY_SCOPE_AGENT);
    if (old == (unsigned)(ep * 32 - 1)) {  // leader: last of the 32
      __hip_atomic_fetch_add(ctrl, 1u, __ATOMIC_RELAXED, __HIP_MEMORY_SCOPE_AGENT);
      while (__hip_atomic_load(ctrl, __ATOMIC_RELAXED, __HIP_MEMORY_SCOPE_AGENT) <
             (unsigned)(ep * 8))
        __builtin_amdgcn_s_sleep(8);
      (void)__hip_atomic_load(ctrl, __ATOMIC_ACQUIRE, __HIP_MEMORY_SCOPE_AGENT);
      __hip_atomic_store(xf, (unsigned)ep, __ATOMIC_RELAXED, __HIP_MEMORY_SCOPE_AGENT);
    } else {
      while (__hip_atomic_load(xf, __ATOMIC_RELAXED, __HIP_MEMORY_SCOPE_AGENT) <
             (unsigned)ep)
        __builtin_amdgcn_s_sleep(8);
      (void)__hip_atomic_load(xf, __ATOMIC_ACQUIRE, __HIP_MEMORY_SCOPE_AGENT);
    }
  }
  __syncthreads();
}

// -------- 64xBN MFMA GEMM tile, 8 waves, dbuf LDS + XOR swizzle (T2) --------
// BN=128: 2Mx4N waves of 32x32 (acc 2x2). BN=64: 4Mx2N waves of 16x32 (acc 1x2).
template <int FLAGS, int BN>
static __device__ void gtile(u16* As, u16* Bs,
    const u16* __restrict__ A, const u16* __restrict__ Bt,
    float* __restrict__ Cf, u16* __restrict__ Cb,
    const float* __restrict__ Cadd, const float* __restrict__ bias,
    const float* __restrict__ scale, const float* __restrict__ shift,
    int N, int K, int bx, int by) {
  const int tid = threadIdx.x;
  const int wave = tid >> 6, lane = tid & 63;
  const int bm = by << 6, bn = bx * BN;
  const int lr = lane & 15, lg = lane >> 4;
  const int rx = lr & 7;
  const int wm = (BN == 128) ? ((wave >> 2) << 5) : ((wave >> 1) << 4);
  const int wn = (BN == 128) ? ((wave & 3) << 5) : ((wave & 1) << 5);
  constexpr int MI = (BN == 128) ? 2 : 1;
  constexpr int NB = BN / 64;

  f32x4 acc[MI][2] = {};

  auto stage = [&](int buf, int kt) {
    { const int row = tid >> 3;
      const int cg = (tid & 7) ^ (row & 7);
      __builtin_amdgcn_global_load_lds(
          (gvoid_t*)(A + (size_t)(bm + row) * K + kt + (cg << 3)),
          (lvoid_t*)(As + buf * 4096 + wave * 512), 16, 0, 0); }
#pragma unroll
    for (int i = 0; i < NB; ++i) {
      const int li = i * 512 + tid;
      const int row = li >> 3;
      const int cg = (li & 7) ^ (row & 7);
      __builtin_amdgcn_global_load_lds(
          (gvoid_t*)(Bt + (size_t)(bn + row) * K + kt + (cg << 3)),
          (lvoid_t*)(Bs + buf * (BN * 64) + i * 4096 + wave * 512), 16, 0, 0);
    }
  };

  stage(0, 0);
  int buf = 0;
  for (int kt = 0; kt < K; kt += 64) {
    __syncthreads();                       // buf staged; prev reads done
    if (kt + 64 < K) stage(buf ^ 1, kt + 64);
    const u16* Ab = As + buf * 4096;
    const u16* Bb = Bs + buf * (BN * 64);
#pragma unroll
    for (int kk = 0; kk < 64; kk += 32) {
      bf16x8 av[MI], bv[2];
#pragma unroll
      for (int mi2 = 0; mi2 < MI; ++mi2)
        av[mi2] = *(const bf16x8*)(Ab + ((wm + mi2 * 16 + lr) << 6) +
                                   ((((kk >> 3) + lg) ^ rx) << 3));
#pragma unroll
      for (int ni = 0; ni < 2; ++ni)
        bv[ni] = *(const bf16x8*)(Bb + ((wn + ni * 16 + lr) << 6) +
                                  ((((kk >> 3) + lg) ^ rx) << 3));
#pragma unroll
      for (int mi2 = 0; mi2 < MI; ++mi2)
#pragma unroll
        for (int ni = 0; ni < 2; ++ni)
          acc[mi2][ni] = __builtin_amdgcn_mfma_f32_16x16x32_bf16(av[mi2], bv[ni], acc[mi2][ni], 0, 0, 0);
    }
    buf ^= 1;
  }

#pragma unroll
  for (int mi2 = 0; mi2 < MI; ++mi2) {
#pragma unroll
    for (int ni = 0; ni < 2; ++ni) {
      const int col = bn + wn + ni * 16 + lr;
#pragma unroll
      for (int r = 0; r < 4; ++r) {
        const int row = bm + wm + mi2 * 16 + (lg << 2) + r;
        float v = acc[mi2][ni][r];
        if (FLAGS & E_FINAL) {
          if (col < 51)
            Cf[row * 51 + col] = v * (1.f / 6.f) + Cadd[(row << 7) + col] + scale[row * 51 + col];
        } else {
          if (FLAGS & E_CADD) v += Cadd[(size_t)row * N + col];
          if (FLAGS & E_BIAS) v += bias[col];
          if (FLAGS & E_RELU) v = fmaxf(v, 0.f);
          if (FLAGS & E_AFF) v = v * scale[col] + shift[col];
          if (FLAGS & E_WF32) Cf[(size_t)row * N + col] = v;
          if (FLAGS & E_WBF) Cb[(size_t)row * N + col] = f2bf(v);
        }
      }
    }
  }
  __syncthreads();                         // protect LDS reuse by next job
}

// -------- phase bodies --------
static __device__ void fm_body(const MegaArgs& a, int b, int st) {
  const int d0 = st << 2;
  const float* p = a.fm + (size_t)b * 102400 + d0;
  float s0 = 0, s1 = 0, s2 = 0, s3 = 0;
  for (int pp = 0; pp < 100; ++pp) {
    const float4 v = *(const float4*)(p + pp * 1024);
    if (a.use_fmb) {
      ushort4 u;
      u.x = f2bf(v.x); u.y = f2bf(v.y); u.z = f2bf(v.z); u.w = f2bf(v.w);
      *(ushort4*)(a.fmb + (size_t)b * 102400 + pp * 1024 + d0) = u;
    }
    s0 += v.x; s1 += v.y; s2 += v.z; s3 += v.w;
  }
  const float inv = 1.0f / 100.0f;
  s0 *= inv; s1 *= inv; s2 *= inv; s3 *= inv;
  const int o = (b << 10) + d0;
  float4 m; m.x = s0; m.y = s1; m.z = s2; m.w = s3;
  *(float4*)(a.vis_sum + o) = m;
  ushort4 u; u.x = f2bf(s0); u.y = f2bf(s1); u.z = f2bf(s2); u.w = f2bf(s3);
  *(ushort4*)(a.visb + o) = u;
}

static __device__ void prep_body(const MegaArgs& a, int b, int st, float (*t)[65]) {
  const float* in; u16* out; int ld, k0, K, Nv, kT;
  int bb = b;
  if (bb < 1024)      {            in = a.W1; out = a.W1nv_t; ld = 2048; k0 = 0;    K = 2048; Nv = 2048; kT = 32; }
  else if (bb < 1536) { bb -= 1024; in = a.W1; out = a.W1v_t;  ld = 2048; k0 = 2048; K = 1024; Nv = 2048; kT = 16; }
  else if (bb < 2048) { bb -= 1536; in = a.W2; out = a.W2t;   ld = 1024; k0 = 0;    K = 2048; Nv = 1024; kT = 32; }
  else if (bb < 2816) { bb -= 2048; in = a.Wk; out = a.Wkt;   ld = 3072; k0 = 0;    K = 1024; Nv = 3072; kT = 16; }
  else if (bb < 3584) { bb -= 2816; in = a.Uk; out = a.Ukt;   ld = 3072; k0 = 0;    K = 1024; Nv = 3072; kT = 16; }
  else if (bb < 3648) { bb -= 3584; in = a.Ws; out = a.Wsnv_t; ld = 51;  k0 = 0;    K = 2048; Nv = 51;   kT = 32; }
  else                { bb -= 3648; in = a.Ws; out = a.Wsv_t;  ld = 51;  k0 = 2048; K = 1024; Nv = 51;   kT = 16; }
  const int kt = (bb % kT) << 6, nt = (bb / kT) << 6;
  const int tx = st & 63, ty = st >> 6;
#pragma unroll
  for (int i = 0; i < 16; ++i) {
    const int kl = ty + i * 4;
    const int n = nt + tx;
    t[kl][tx] = (n < Nv) ? in[(size_t)(k0 + kt + kl) * ld + n] : 0.f;
  }
  __syncthreads();
#pragma unroll
  for (int i = 0; i < 16; ++i)
    out[(size_t)(nt + ty + i * 4) * K + kt + tx] = f2bf(t[tx][ty + i * 4]);
}

static __device__ void misc_elem(int i, const MegaArgs& a) {
  if (i < 2097152) a.nonvis_b[i] = f2bf(a.nonvis[i]);
  if (i < 1048576) { a.hf[i] = 0.f; a.hb[i] = 0; }
  if (i < 2048) { float sc = a.g1[i] * rsqrtf(a.v1[i] + 1e-3f); a.scale1[i] = sc; a.shift1[i] = a.be1[i] - a.m1[i] * sc; }
  if (i < 1024) { float sc = a.g2[i] * rsqrtf(a.v2[i] + 1e-3f); a.scale2[i] = sc; a.shift2[i] = a.be2[i] - a.m2[i] * sc; }
  if (i < 128) a.bs_pad[i] = (i < 51) ? a.bs[i] : 0.f;
}

// convT weight packing: even out-pixel p: w[0]*x[p/2-1] + w[2]*x[p/2]; odd: w[1]*x[(p-1)/2]
static __device__ void build_elem(long idx, const MegaArgs& a) {
  const float* w; const float* bin; u16* wp; float* bp; int Si, CI, CO; long base;
  if (idx < 1048576)      { base = 0;       w = a.ct1w; bin = a.ct1b; wp = a.Wp1; bp = a.bp1; Si = 1; CI = 1024; CO = 256; }
  else if (idx < 2097152) { base = 1048576; w = a.ct2w; bin = a.ct2b; wp = a.Wp2; bp = a.bp2; Si = 2; CI = 256;  CO = 64; }
  else if (idx < 3145728) { base = 2097152; w = a.ct3w; bin = a.ct3b; wp = a.Wp3; bp = a.bp3; Si = 4; CI = 64;   CO = 16; }
  else                    { base = 3145728; w = a.ct4w; bin = a.ct4b; wp = a.Wp4; bp = a.bp4; Si = 8; CI = 16;   CO = 1; }
  const long r = idx - base;
  const int n = (int)(r >> 10), k = (int)(r & 1023);
  const int So = Si * 2;
  const int co = n % CO;
  const int pox = (n / CO) % So;
  const int poy = n / (CO * So);
  const int ci = k % CI;
  const int pix = (k / CI) % Si;
  const int piy = k / (CI * Si);
  int wy = -1, wx = -1;
  if (poy & 1) { if (piy == (poy >> 1)) wy = 1; }
  else { if (piy == (poy >> 1)) wy = 2; else if (piy == (poy >> 1) - 1) wy = 0; }
  if (pox & 1) { if (pix == (pox >> 1)) wx = 1; }
  else { if (pix == (pox >> 1)) wx = 2; else if (pix == (pox >> 1) - 1) wx = 0; }
  float v = 0.f;
  if (wy >= 0 && wx >= 0) v = w[((size_t)(wy * 3 + wx) * CI + ci) * CO + co];
  wp[(size_t)n * 1024 + k] = f2bf(v);
  if (k == 0) bp[n] = bin[co];
}

static __device__ void gru_elem(int idx, const MegaArgs& a, int it) {
  const int b = idx >> 10, d = idx & 1023;
  const float* mxb = a.mx + (size_t)b * 3072;
  const float xz = mxb[d], xr = mxb[d + 1024], xh = mxb[d + 2048];
  float iz, ir, ih;
  if (it == 0) { iz = a.br[d]; ir = a.br[d + 1024]; ih = a.br[d + 2048]; }
  else {
    const float* mib = a.mi + (size_t)b * 3072;
    iz = mib[d]; ir = mib[d + 1024]; ih = mib[d + 2048];
  }
  const float zg = 1.f / (1.f + expf(-(xz + iz)));
  const float rg = 1.f / (1.f + expf(-(xr + ir)));
  const float hh = tanhf(xh + rg * ih);
  const float hn = zg * a.hf[idx] + (1.f - zg) * hh;
  a.hf[idx] = hn;
  a.hb[idx] = f2bf(hn);
}

static __device__ __forceinline__ void taps(int o, int& si, float* w) {
  const float s = 1.6f * (float)o + 0.3f;
  int s0 = (int)ceilf(s - 1.6f);
  if (s0 < 0) s0 = 0;
  si = s0;
  float sum = 0.f;
#pragma unroll
  for (int j = 0; j < 4; ++j) {
    const int i = s0 + j;
    float ww = 0.f;
    if (i <= 15) {
      const float d = fabsf(s - (float)i) * (1.0f / 1.6f);
      ww = fmaxf(0.f, 1.f - d);
    }
    w[j] = ww;
    sum += ww;
  }
  const float inv = 1.f / sum;
#pragma unroll
  for (int j = 0; j < 4; ++j) w[j] *= inv;
}

// -------- fused: bilinear+softmax for job j's 2 batches, then wsum -----------
static __device__ void attn_wsum_job(const MegaArgs& a, int j, char* arena) {
  float* sm = (float*)arena;              // 512 floats
  float* at = (float*)(arena + 2048);     // 2 x 128 floats
  const int tid = threadIdx.x;
  const int sub = tid >> 8, st = tid & 255;
  const int b = j * 2 + sub;
  float val = -1e30f;
  if (st < 100) {
    const int oy = st / 10, ox = st - oy * 10;
    int siy, six;
    float wy[4], wx[4];
    taps(oy, siy, wy);
    taps(ox, six, wx);
    const float* p = a.a4 + (b << 8);
    float s = 0.f;
#pragma unroll
    for (int jy = 0; jy < 4; ++jy) {
      const int iy = min(siy + jy, 15);
      float rs = 0.f;
#pragma unroll
      for (int jx = 0; jx < 4; ++jx) {
        const int ix = min(six + jx, 15);
        rs += wx[jx] * p[(iy << 4) + ix];
      }
      s += wy[jy] * rs;
    }
    val = s;
  }
  sm[tid] = val;
  __syncthreads();
  for (int off = 128; off > 0; off >>= 1) {
    if (st < off) sm[tid] = fmaxf(sm[tid], sm[tid + off]);
    __syncthreads();
  }
  const float mxv = sm[sub << 8];
  __syncthreads();
  const float e = (st < 100) ? expf(val - mxv) : 0.f;
  sm[tid] = e;
  __syncthreads();
  for (int off = 128; off > 0; off >>= 1) {
    if (st < off) sm[tid] += sm[tid + off];
    __syncthreads();
  }
  if (st < 100) at[(sub << 7) + st] = e / sm[sub << 8];
  __syncthreads();
  // ---- wsum for batch b ----
  const int d0 = st << 2;
  float s0 = 0, s1 = 0, s2 = 0, s3 = 0;
  if (a.use_fmb) {
    const u16* p = a.fmb + (size_t)b * 102400 + d0;
    for (int pp = 0; pp < 100; ++pp) {
      const ushort4 v = *(const ushort4*)(p + pp * 1024);
      const float aa = at[(sub << 7) + pp];
      s0 += aa * bf2f(v.x); s1 += aa * bf2f(v.y); s2 += aa * bf2f(v.z); s3 += aa * bf2f(v.w);
    }
  } else {
    const float* p = a.fm + (size_t)b * 102400 + d0;
    for (int pp = 0; pp < 100; ++pp) {
      const float4 v = *(const float4*)(p + pp * 1024);
      const float aa = at[(sub << 7) + pp];
      s0 += aa * v.x; s1 += aa * v.y; s2 += aa * v.z; s3 += aa * v.w;
    }
  }
  const int o = (b << 10) + d0;
  float4 vs = *(float4*)(a.vis_sum + o);
  vs.x += s0; vs.y += s1; vs.z += s2; vs.w += s3;
  *(float4*)(a.vis_sum + o) = vs;
  ushort4 u; u.x = f2bf(s0); u.y = f2bf(s1); u.z = f2bf(s2); u.w = f2bf(s3);
  *(ushort4*)(a.visb + o) = u;
  ushort4 w; w.x = f2bf(vs.x); w.y = f2bf(vs.y); w.z = f2bf(vs.z); w.w = f2bf(vs.w);
  *(ushort4*)(a.vsb + o) = w;
  __syncthreads();  // at/sm reuse by next job
}

// -------- the mega kernel: whole net, one launch --------
__global__ __launch_bounds__(THREADS) void mega_k(MegaArgs a) {
  __shared__ char arena[49152];
  u16* As = (u16*)arena;
  u16* Bs = (u16*)(arena + 16384);
  const int tid = threadIdx.x;
  const int bid = blockIdx.x;
  const int grp = bid & 7;
  int ep = 0;

  // ---- PS1: fm_pass + weight transposes + convT packing + misc ----
  for (int j = bid; j < 3024; j += GRID) {
    if (j < 512) {
      const int sub = tid >> 8, st = tid & 255;
      fm_body(a, j * 2 + sub, st);
    } else if (j < 2352) {
      const int sub = tid >> 8, st = tid & 255;
      prep_body(a, (j - 512) * 2 + sub, st, (float(*)[65])(arena + sub * 16640));
    } else if (j < 2608) {
      const int base = (j - 2352) * 8192;
#pragma unroll
      for (int r = 0; r < 16; ++r) misc_elem(base + r * 512 + tid, a);
    } else {
      const long base = (long)(j - 2608) * 8192;
#pragma unroll
      for (int r = 0; r < 16; ++r) build_elem(base + r * 512 + tid, a);
    }
    __syncthreads();
  }
  ++ep; gbar2(a.ctrl, grp, ep);

  // ---- PS2: P1 = nonvis@W1nv + b1 (256 tiles); snv = nonvis@Wsnv + bs (16) ----
  for (int j = bid; j < 272; j += GRID) {
    if (j < 256)
      gtile<E_BIAS | E_WF32, 128>(As, Bs, a.nonvis_b, a.W1nv_t, a.P1, nullptr, nullptr,
                                  a.b1, nullptr, nullptr, 2048, 2048, j & 15, j >> 4);
    else
      gtile<E_BIAS | E_WF32, 128>(As, Bs, a.nonvis_b, a.Wsnv_t, a.snv, nullptr, nullptr,
                                  a.bs_pad, nullptr, nullptr, 128, 2048, 0, j - 256);
  }
  ++ep; gbar2(a.ctrl, grp, ep);

  // ---- 5 iterations ----
  for (int it = 0; it < 5; ++it) {
    // PA: x1 = bn(relu(visb@W1v + P1))   (256 jobs, 1/block)
    for (int j = bid; j < 256; j += GRID)
      gtile<E_CADD | E_RELU | E_AFF | E_WBF, 128>(As, Bs, a.visb, a.W1v_t, nullptr, a.x1,
                                                  a.P1, nullptr, a.scale1, a.shift1,
                                                  2048, 1024, j & 15, j >> 4);
    ++ep; gbar2(a.ctrl, grp, ep);
    // PB: x2 = bn(relu(x1@W2 + b2))   (BN=64: 256 jobs, 1/block)
    for (int j = bid; j < 256; j += GRID)
      gtile<E_BIAS | E_RELU | E_AFF | E_WBF, 64>(As, Bs, a.x1, a.W2t, nullptr, a.x2,
                                                 nullptr, a.b2, a.scale2, a.shift2,
                                                 1024, 2048, j & 15, j >> 4);
    ++ep; gbar2(a.ctrl, grp, ep);
    // PC: mx = x2@Wk + bi   (BN=64: 768 jobs, 3/block)
    for (int j = bid; j < 768; j += GRID)
      gtile<E_BIAS | E_WF32, 64>(As, Bs, a.x2, a.Wkt, a.mx, nullptr, nullptr, a.bi,
                                 nullptr, nullptr, 3072, 1024, j % 48, j / 48);
    ++ep; gbar2(a.ctrl, grp, ep);
    // PD: gru (it==0: mi == br since h==0)
    for (int i = bid * THREADS + tid; i < 1048576; i += GRID * THREADS)
      gru_elem(i, a, it);
    ++ep; gbar2(a.ctrl, grp, ep);
    // PE: c1 = relu(hb@Wp1 + bp1) (256) + mi' = hb@Uk + br (768) -> 4/block
    {
      const int nj = (it < 4) ? 1024 : 256;
      for (int j = bid; j < nj; j += GRID) {
        if (j < 256)
          gtile<E_BIAS | E_RELU | E_WBF, 64>(As, Bs, a.hb, a.Wp1, nullptr, a.a1,
                                             nullptr, a.bp1, nullptr, nullptr,
                                             1024, 1024, j & 15, j >> 4);
        else {
          const int t2 = j - 256;
          gtile<E_BIAS | E_WF32, 64>(As, Bs, a.hb, a.Ukt, a.mi, nullptr, nullptr, a.br,
                                     nullptr, nullptr, 3072, 1024, t2 % 48, t2 / 48);
        }
      }
    }
    ++ep; gbar2(a.ctrl, grp, ep);
    // PF: c2   (BN=64: 256 jobs)
    for (int j = bid; j < 256; j += GRID)
      gtile<E_BIAS | E_RELU | E_WBF, 64>(As, Bs, a.a1, a.Wp2, nullptr, a.a2, nullptr,
                                         a.bp2, nullptr, nullptr, 1024, 1024, j & 15, j >> 4);
    ++ep; gbar2(a.ctrl, grp, ep);
    // PG: c3   (BN=64: 256 jobs)
    for (int j = bid; j < 256; j += GRID)
      gtile<E_BIAS | E_RELU | E_WBF, 64>(As, Bs, a.a2, a.Wp3, nullptr, a.a3, nullptr,
                                         a.bp3, nullptr, nullptr, 1024, 1024, j & 15, j >> 4);
    ++ep; gbar2(a.ctrl, grp, ep);
    // PH: c4 -> a4 (1024 x 256 fp32)   (BN=64: 64 jobs)
    for (int j = bid; j < 64; j += GRID)
      gtile<E_BIAS | E_WF32, 64>(As, Bs, a.a3, a.Wp4, a.a4, nullptr, nullptr, a.bp4,
                                 nullptr, nullptr, 256, 1024, j & 3, j >> 2);
    ++ep; gbar2(a.ctrl, grp, ep);
    // PIJ: bilinear+softmax (in-LDS) then wsum; 512 jobs x 2 batches
    for (int j = bid; j < 512; j += GRID)
      attn_wsum_job(a, j, arena);
    ++ep; gbar2(a.ctrl, grp, ep);
  }

  // PZ: out = (vsb@Wsv)/6 + snv + prior  (fused epilogue)
  for (int j = bid; j < 16; j += GRID)
    gtile<E_FINAL, 128>(As, Bs, a.vsb, a.Wsv_t, a.out, nullptr, a.snv, nullptr,
                        a.prior, nullptr, 128, 1024, 0, j);
}

extern "C" void kernel_launch(void* const* d_in, const int* in_sizes, int n_in,
                              void* d_out, int out_size, void* d_ws, size_t ws_size,
                              hipStream_t stream) {
  (void)in_sizes; (void)n_in; (void)out_size;
  MegaArgs a;
  a.nonvis = (const float*)d_in[0];  a.fm   = (const float*)d_in[1];
  a.prior  = (const float*)d_in[2];  a.W1   = (const float*)d_in[3];
  a.b1  = (const float*)d_in[4];     a.g1   = (const float*)d_in[5];
  a.be1 = (const float*)d_in[6];     a.m1   = (const float*)d_in[7];
  a.v1  = (const float*)d_in[8];     a.W2   = (const float*)d_in[9];
  a.b2  = (const float*)d_in[10];    a.g2   = (const float*)d_in[11];
  a.be2 = (const float*)d_in[12];    a.m2   = (const float*)d_in[13];
  a.v2  = (const float*)d_in[14];    a.Wk   = (const float*)d_in[15];
  a.Uk  = (const float*)d_in[16];    a.bi   = (const float*)d_in[17];
  a.br  = (const float*)d_in[18];    a.ct1w = (const float*)d_in[19];
  a.ct1b = (const float*)d_in[20];   a.ct2w = (const float*)d_in[21];
  a.ct2b = (const float*)d_in[22];   a.ct3w = (const float*)d_in[23];
  a.ct3b = (const float*)d_in[24];   a.ct4w = (const float*)d_in[25];
  a.ct4b = (const float*)d_in[26];   a.Ws   = (const float*)d_in[27];
  a.bs  = (const float*)d_in[28];

  char* base = (char*)d_ws;
  size_t off = 0;
  auto alloc = [&](size_t bytes) -> void* {
    void* r = base + off;
    off = (off + bytes + 255) & ~(size_t)255;
    return r;
  };

  a.ctrl     = (unsigned*)alloc(4096);
  a.nonvis_b = (u16*)alloc(4194304);
  a.W1nv_t   = (u16*)alloc(8388608);
  a.W1v_t    = (u16*)alloc(4194304);
  a.W2t      = (u16*)alloc(4194304);
  a.Wkt      = (u16*)alloc(6291456);
  a.Ukt      = (u16*)alloc(6291456);
  a.Wsnv_t   = (u16*)alloc(524288);
  a.Wsv_t    = (u16*)alloc(262144);
  a.Wp1      = (u16*)alloc(2097152);
  a.Wp2      = (u16*)alloc(2097152);
  a.Wp3      = (u16*)alloc(2097152);
  a.Wp4      = (u16*)alloc(524288);
  a.bp1      = (float*)alloc(4096);
  a.bp2      = (float*)alloc(4096);
  a.bp3      = (float*)alloc(4096);
  a.bp4      = (float*)alloc(1024);
  a.scale1   = (float*)alloc(8192);
  a.shift1   = (float*)alloc(8192);
  a.scale2   = (float*)alloc(4096);
  a.shift2   = (float*)alloc(4096);
  a.bs_pad   = (float*)alloc(512);
  a.P1       = (float*)alloc(8388608);
  a.snv      = (float*)alloc(524288);
  a.x1       = (u16*)alloc(4194304);
  a.x2       = (u16*)alloc(2097152);
  a.mx       = (float*)alloc(12582912);
  a.mi       = (float*)alloc(12582912);
  a.hf       = (float*)alloc(4194304);
  a.hb       = (u16*)alloc(2097152);
  a.a1       = (u16*)alloc(2097152);
  a.a2       = (u16*)alloc(2097152);
  a.a3       = (u16*)alloc(2097152);
  a.a4       = (float*)alloc(1048576);
  a.vis_sum  = (float*)alloc(4194304);
  a.visb     = (u16*)alloc(2097152);
  a.vsb      = (u16*)alloc(2097152);
  a.out      = (float*)d_out;
  a.fmb = nullptr;
  a.use_fmb = 0;
  if (off + (size_t)209715200 + 256 <= ws_size) {
    a.fmb = (u16*)alloc(209715200);
    a.use_fmb = 1;
  }

  hipMemsetAsync(a.ctrl, 0, 4096, stream);
  mega_k<<<GRID, THREADS, 0, stream>>>(a);
}

// Round 8
// 1609.690 us; speedup vs baseline: 3.8810x; 1.0539x over previous
//
#include <hip/hip_runtime.h>

typedef unsigned short u16;
typedef __attribute__((ext_vector_type(8))) __bf16 bf16x8;
typedef __attribute__((ext_vector_type(4))) float f32x4;

typedef __attribute__((address_space(1))) const void gvoid_t;
typedef __attribute__((address_space(3))) void lvoid_t;

enum { E_CADD = 1, E_BIAS = 2, E_RELU = 4, E_AFF = 8, E_WBF = 16, E_WF32 = 32, E_FINAL = 64 };

#define GRID 256
#define THREADS 512

static __device__ __forceinline__ u16 f2bf(float f) {
  unsigned u = __float_as_uint(f);
  u += 0x7fffu + ((u >> 16) & 1u);
  return (u16)(u >> 16);
}
static __device__ __forceinline__ float bf2f(u16 h) {
  return __uint_as_float(((unsigned)h) << 16);
}

struct MegaArgs {
  const float *nonvis, *fm, *prior, *W1, *b1, *g1, *be1, *m1, *v1;
  const float *W2, *b2, *g2, *be2, *m2, *v2, *Wk, *Uk, *bi, *br;
  const float *ct1w, *ct1b, *ct2w, *ct2b, *ct3w, *ct3b, *ct4w, *ct4b, *Ws, *bs;
  u16 *nonvis_b, *W1nv_t, *W1v_t, *W2t, *Wkt, *Ukt, *Wsnv_t, *Wsv_t;
  u16 *Wp1, *Wp2, *Wp3, *Wp4;
  float *bp1, *bp2, *bp3, *bp4, *scale1, *shift1, *scale2, *shift2, *bs_pad;
  float *P1, *snv, *mx, *mi, *hf;
  u16 *x1, *x2, *hb, *a1, *a2, *a3;
  float *a4, *vis_sum;
  u16 *visb, *vsb, *fmb;
  float *out;
  unsigned *ctrl;
  int use_fmb;
};

// ---- two-level device-scope grid barrier (R6-proven) ------------------------
static __device__ __forceinline__ void gbar2(unsigned* ctrl, int grp, int ep) {
  __syncthreads();
  if (threadIdx.x == 0) {
    unsigned* xc = ctrl + 32 + 32 * grp;   // group arrival counter (128B apart)
    unsigned* xf = ctrl + 320 + 32 * grp;  // group gate
    const unsigned old =
        __hip_atomic_fetch_add(xc, 1u, __ATOMIC_RELEASE, __HIP_MEMORY_SCOPE_AGENT);
    if (old == (unsigned)(ep * 32 - 1)) {  // leader: last of the 32
      __hip_atomic_fetch_add(ctrl, 1u, __ATOMIC_RELAXED, __HIP_MEMORY_SCOPE_AGENT);
      while (__hip_atomic_load(ctrl, __ATOMIC_RELAXED, __HIP_MEMORY_SCOPE_AGENT) <
             (unsigned)(ep * 8))
        __builtin_amdgcn_s_sleep(2);
      (void)__hip_atomic_load(ctrl, __ATOMIC_ACQUIRE, __HIP_MEMORY_SCOPE_AGENT);
      __hip_atomic_store(xf, (unsigned)ep, __ATOMIC_RELAXED, __HIP_MEMORY_SCOPE_AGENT);
    } else {
      while (__hip_atomic_load(xf, __ATOMIC_RELAXED, __HIP_MEMORY_SCOPE_AGENT) <
             (unsigned)ep)
        __builtin_amdgcn_s_sleep(2);
      (void)__hip_atomic_load(xf, __ATOMIC_ACQUIRE, __HIP_MEMORY_SCOPE_AGENT);
    }
  }
  __syncthreads();
}

// -------- 64x64 tile, 8 waves, 4-buffer 3-deep pipeline, counted vmcnt -------
// Per step: vmcnt(4) [oldest stage's 2 loads done] -> s_barrier -> issue
// stage(s+3) into buf (s+3)&3 (== buf read at step s-1; all waves consumed it
// before reaching this barrier) -> ds_read+MFMA. nsteps%4==0 so the last step
// reads buf 3, and a following job's prologue (bufs 0,1,2) cannot race it.
template <int FLAGS>
static __device__ void gtile64(u16* arena_u16,
    const u16* __restrict__ A, const u16* __restrict__ Bt,
    float* __restrict__ Cf, u16* __restrict__ Cb,
    const float* __restrict__ Cadd, const float* __restrict__ bias,
    const float* __restrict__ scale, const float* __restrict__ shift,
    int N, int K, int bx, int by) {
  const int tid = threadIdx.x;
  const int wave = tid >> 6, lane = tid & 63;
  const int bm = by << 6, bn = bx << 6;
  const int lr = lane & 15, lg = lane >> 4;
  const int rx = lr & 7;
  const int wm = (wave >> 1) << 4, wn = (wave & 1) << 5;

  f32x4 acc[2] = {};

  const int row = tid >> 3;
  const int cg = (tid & 7) ^ (row & 7);          // pre-swizzled source col-grp
  const u16* gA = A + (size_t)(bm + row) * K + (cg << 3);
  const u16* gB = Bt + (size_t)(bn + row) * K + (cg << 3);
  const int lofs = wave * 512;                   // wave-uniform LDS base (elems)

  auto stage = [&](int buf, int kt) {
    u16* base = arena_u16 + buf * 8192;
    __builtin_amdgcn_global_load_lds((gvoid_t*)(gA + kt), (lvoid_t*)(base + lofs), 16, 0, 0);
    __builtin_amdgcn_global_load_lds((gvoid_t*)(gB + kt), (lvoid_t*)(base + 4096 + lofs), 16, 0, 0);
  };

  stage(0, 0); stage(1, 64); stage(2, 128);
  const int nsteps = K >> 6;
  for (int s = 0; s < nsteps; ++s) {
    const int rem = nsteps - 1 - s;
    if (rem >= 2)      asm volatile("s_waitcnt vmcnt(4)" ::: "memory");
    else if (rem == 1) asm volatile("s_waitcnt vmcnt(2)" ::: "memory");
    else               asm volatile("s_waitcnt vmcnt(0)" ::: "memory");
    __builtin_amdgcn_s_barrier();
    if (s + 3 < nsteps) stage((s + 3) & 3, (s + 3) << 6);
    const u16* Ab = arena_u16 + (s & 3) * 8192;
    const u16* Bb = Ab + 4096;
#pragma unroll
    for (int kk = 0; kk < 64; kk += 32) {
      const int sw = ((((kk >> 3) + lg) ^ rx) << 3);
      bf16x8 av = *(const bf16x8*)(Ab + ((wm + lr) << 6) + sw);
      bf16x8 bv0 = *(const bf16x8*)(Bb + ((wn + lr) << 6) + sw);
      bf16x8 bv1 = *(const bf16x8*)(Bb + ((wn + 16 + lr) << 6) + sw);
      acc[0] = __builtin_amdgcn_mfma_f32_16x16x32_bf16(av, bv0, acc[0], 0, 0, 0);
      acc[1] = __builtin_amdgcn_mfma_f32_16x16x32_bf16(av, bv1, acc[1], 0, 0, 0);
    }
  }

#pragma unroll
  for (int ni = 0; ni < 2; ++ni) {
    const int col = bn + wn + ni * 16 + lr;
#pragma unroll
    for (int r = 0; r < 4; ++r) {
      const int rw = bm + wm + (lg << 2) + r;
      float v = acc[ni][r];
      if (FLAGS & E_CADD) v += Cadd[(size_t)rw * N + col];
      if (FLAGS & E_BIAS) v += bias[col];
      if (FLAGS & E_RELU) v = fmaxf(v, 0.f);
      if (FLAGS & E_AFF) v = v * scale[col] + shift[col];
      if (FLAGS & E_WF32) Cf[(size_t)rw * N + col] = v;
      if (FLAGS & E_WBF) Cb[(size_t)rw * N + col] = f2bf(v);
    }
  }
  __syncthreads();                       // LDS safe for next job / phase body
}

// -------- 64x128 tile, 2-buffer (setup/final phases only) --------------------
template <int FLAGS>
static __device__ void gtile128(u16* arena_u16,
    const u16* __restrict__ A, const u16* __restrict__ Bt,
    float* __restrict__ Cf, u16* __restrict__ Cb,
    const float* __restrict__ Cadd, const float* __restrict__ bias,
    const float* __restrict__ scale, const float* __restrict__ shift,
    int N, int K, int bx, int by) {
  u16* As = arena_u16;             // 2 x 4096 elems
  u16* Bs = arena_u16 + 8192;      // 2 x 8192 elems
  const int tid = threadIdx.x;
  const int wave = tid >> 6, lane = tid & 63;
  const int bm = by << 6, bn = bx << 7;
  const int lr = lane & 15, lg = lane >> 4;
  const int rx = lr & 7;
  const int wm = (wave >> 2) << 5, wn = (wave & 3) << 5;

  f32x4 acc[2][2] = {};

  auto stage = [&](int buf, int kt) {
    { const int row = tid >> 3;
      const int cg = (tid & 7) ^ (row & 7);
      __builtin_amdgcn_global_load_lds(
          (gvoid_t*)(A + (size_t)(bm + row) * K + kt + (cg << 3)),
          (lvoid_t*)(As + buf * 4096 + wave * 512), 16, 0, 0); }
#pragma unroll
    for (int i = 0; i < 2; ++i) {
      const int li = i * 512 + tid;
      const int row = li >> 3;
      const int cg = (li & 7) ^ (row & 7);
      __builtin_amdgcn_global_load_lds(
          (gvoid_t*)(Bt + (size_t)(bn + row) * K + kt + (cg << 3)),
          (lvoid_t*)(Bs + buf * 8192 + i * 4096 + wave * 512), 16, 0, 0);
    }
  };

  stage(0, 0);
  int buf = 0;
  for (int kt = 0; kt < K; kt += 64) {
    __syncthreads();
    if (kt + 64 < K) stage(buf ^ 1, kt + 64);
    const u16* Ab = As + buf * 4096;
    const u16* Bb = Bs + buf * 8192;
#pragma unroll
    for (int kk = 0; kk < 64; kk += 32) {
      bf16x8 av[2], bv[2];
#pragma unroll
      for (int mi2 = 0; mi2 < 2; ++mi2)
        av[mi2] = *(const bf16x8*)(Ab + ((wm + mi2 * 16 + lr) << 6) +
                                   ((((kk >> 3) + lg) ^ rx) << 3));
#pragma unroll
      for (int ni = 0; ni < 2; ++ni)
        bv[ni] = *(const bf16x8*)(Bb + ((wn + ni * 16 + lr) << 6) +
                                  ((((kk >> 3) + lg) ^ rx) << 3));
#pragma unroll
      for (int mi2 = 0; mi2 < 2; ++mi2)
#pragma unroll
        for (int ni = 0; ni < 2; ++ni)
          acc[mi2][ni] = __builtin_amdgcn_mfma_f32_16x16x32_bf16(av[mi2], bv[ni], acc[mi2][ni], 0, 0, 0);
    }
    buf ^= 1;
  }

#pragma unroll
  for (int mi2 = 0; mi2 < 2; ++mi2) {
#pragma unroll
    for (int ni = 0; ni < 2; ++ni) {
      const int col = bn + wn + ni * 16 + lr;
#pragma unroll
      for (int r = 0; r < 4; ++r) {
        const int rw = bm + wm + mi2 * 16 + (lg << 2) + r;
        float v = acc[mi2][ni][r];
        if (FLAGS & E_FINAL) {
          if (col < 51)
            Cf[rw * 51 + col] = v * (1.f / 6.f) + Cadd[(rw << 7) + col] + scale[rw * 51 + col];
        } else {
          if (FLAGS & E_CADD) v += Cadd[(size_t)rw * N + col];
          if (FLAGS & E_BIAS) v += bias[col];
          if (FLAGS & E_RELU) v = fmaxf(v, 0.f);
          if (FLAGS & E_AFF) v = v * scale[col] + shift[col];
          if (FLAGS & E_WF32) Cf[(size_t)rw * N + col] = v;
          if (FLAGS & E_WBF) Cb[(size_t)rw * N + col] = f2bf(v);
        }
      }
    }
  }
  __syncthreads();
}

// -------- phase bodies --------
static __device__ void fm_body(const MegaArgs& a, int b, int st) {
  const int d0 = st << 2;
  const float* p = a.fm + (size_t)b * 102400 + d0;
  float s0 = 0, s1 = 0, s2 = 0, s3 = 0;
  for (int pp = 0; pp < 100; ++pp) {
    const float4 v = *(const float4*)(p + pp * 1024);
    if (a.use_fmb) {
      ushort4 u;
      u.x = f2bf(v.x); u.y = f2bf(v.y); u.z = f2bf(v.z); u.w = f2bf(v.w);
      *(ushort4*)(a.fmb + (size_t)b * 102400 + pp * 1024 + d0) = u;
    }
    s0 += v.x; s1 += v.y; s2 += v.z; s3 += v.w;
  }
  const float inv = 1.0f / 100.0f;
  s0 *= inv; s1 *= inv; s2 *= inv; s3 *= inv;
  const int o = (b << 10) + d0;
  float4 m; m.x = s0; m.y = s1; m.z = s2; m.w = s3;
  *(float4*)(a.vis_sum + o) = m;
  ushort4 u; u.x = f2bf(s0); u.y = f2bf(s1); u.z = f2bf(s2); u.w = f2bf(s3);
  *(ushort4*)(a.visb + o) = u;
}

static __device__ void prep_body(const MegaArgs& a, int b, int st, float (*t)[65]) {
  const float* in; u16* out; int ld, k0, K, Nv, kT;
  int bb = b;
  if (bb < 1024)      {            in = a.W1; out = a.W1nv_t; ld = 2048; k0 = 0;    K = 2048; Nv = 2048; kT = 32; }
  else if (bb < 1536) { bb -= 1024; in = a.W1; out = a.W1v_t;  ld = 2048; k0 = 2048; K = 1024; Nv = 2048; kT = 16; }
  else if (bb < 2048) { bb -= 1536; in = a.W2; out = a.W2t;   ld = 1024; k0 = 0;    K = 2048; Nv = 1024; kT = 32; }
  else if (bb < 2816) { bb -= 2048; in = a.Wk; out = a.Wkt;   ld = 3072; k0 = 0;    K = 1024; Nv = 3072; kT = 16; }
  else if (bb < 3584) { bb -= 2816; in = a.Uk; out = a.Ukt;   ld = 3072; k0 = 0;    K = 1024; Nv = 3072; kT = 16; }
  else if (bb < 3648) { bb -= 3584; in = a.Ws; out = a.Wsnv_t; ld = 51;  k0 = 0;    K = 2048; Nv = 51;   kT = 32; }
  else                { bb -= 3648; in = a.Ws; out = a.Wsv_t;  ld = 51;  k0 = 2048; K = 1024; Nv = 51;   kT = 16; }
  const int kt = (bb % kT) << 6, nt = (bb / kT) << 6;
  const int tx = st & 63, ty = st >> 6;
#pragma unroll
  for (int i = 0; i < 16; ++i) {
    const int kl = ty + i * 4;
    const int n = nt + tx;
    t[kl][tx] = (n < Nv) ? in[(size_t)(k0 + kt + kl) * ld + n] : 0.f;
  }
  __syncthreads();
#pragma unroll
  for (int i = 0; i < 16; ++i)
    out[(size_t)(nt + ty + i * 4) * K + kt + tx] = f2bf(t[tx][ty + i * 4]);
}

static __device__ void misc_elem(int i, const MegaArgs& a) {
  if (i < 2097152) a.nonvis_b[i] = f2bf(a.nonvis[i]);
  if (i < 1048576) { a.hf[i] = 0.f; a.hb[i] = 0; }
  if (i < 2048) { float sc = a.g1[i] * rsqrtf(a.v1[i] + 1e-3f); a.scale1[i] = sc; a.shift1[i] = a.be1[i] - a.m1[i] * sc; }
  if (i < 1024) { float sc = a.g2[i] * rsqrtf(a.v2[i] + 1e-3f); a.scale2[i] = sc; a.shift2[i] = a.be2[i] - a.m2[i] * sc; }
  if (i < 128) a.bs_pad[i] = (i < 51) ? a.bs[i] : 0.f;
}

// convT weight packing: even out-pixel p: w[0]*x[p/2-1] + w[2]*x[p/2]; odd: w[1]*x[(p-1)/2]
static __device__ void build_elem(long idx, const MegaArgs& a) {
  const float* w; const float* bin; u16* wp; float* bp; int Si, CI, CO; long base;
  if (idx < 1048576)      { base = 0;       w = a.ct1w; bin = a.ct1b; wp = a.Wp1; bp = a.bp1; Si = 1; CI = 1024; CO = 256; }
  else if (idx < 2097152) { base = 1048576; w = a.ct2w; bin = a.ct2b; wp = a.Wp2; bp = a.bp2; Si = 2; CI = 256;  CO = 64; }
  else if (idx < 3145728) { base = 2097152; w = a.ct3w; bin = a.ct3b; wp = a.Wp3; bp = a.bp3; Si = 4; CI = 64;   CO = 16; }
  else                    { base = 3145728; w = a.ct4w; bin = a.ct4b; wp = a.Wp4; bp = a.bp4; Si = 8; CI = 16;   CO = 1; }
  const long r = idx - base;
  const int n = (int)(r >> 10), k = (int)(r & 1023);
  const int So = Si * 2;
  const int co = n % CO;
  const int pox = (n / CO) % So;
  const int poy = n / (CO * So);
  const int ci = k % CI;
  const int pix = (k / CI) % Si;
  const int piy = k / (CI * Si);
  int wy = -1, wx = -1;
  if (poy & 1) { if (piy == (poy >> 1)) wy = 1; }
  else { if (piy == (poy >> 1)) wy = 2; else if (piy == (poy >> 1) - 1) wy = 0; }
  if (pox & 1) { if (pix == (pox >> 1)) wx = 1; }
  else { if (pix == (pox >> 1)) wx = 2; else if (pix == (pox >> 1) - 1) wx = 0; }
  float v = 0.f;
  if (wy >= 0 && wx >= 0) v = w[((size_t)(wy * 3 + wx) * CI + ci) * CO + co];
  wp[(size_t)n * 1024 + k] = f2bf(v);
  if (k == 0) bp[n] = bin[co];
}

static __device__ void gru_elem(int idx, const MegaArgs& a, int it) {
  const int b = idx >> 10, d = idx & 1023;
  const float* mxb = a.mx + (size_t)b * 3072;
  const float xz = mxb[d], xr = mxb[d + 1024], xh = mxb[d + 2048];
  float iz, ir, ih;
  if (it == 0) { iz = a.br[d]; ir = a.br[d + 1024]; ih = a.br[d + 2048]; }
  else {
    const float* mib = a.mi + (size_t)b * 3072;
    iz = mib[d]; ir = mib[d + 1024]; ih = mib[d + 2048];
  }
  const float zg = 1.f / (1.f + expf(-(xz + iz)));
  const float rg = 1.f / (1.f + expf(-(xr + ir)));
  const float hh = tanhf(xh + rg * ih);
  const float hn = zg * a.hf[idx] + (1.f - zg) * hh;
  a.hf[idx] = hn;
  a.hb[idx] = f2bf(hn);
}

static __device__ __forceinline__ void taps(int o, int& si, float* w) {
  const float s = 1.6f * (float)o + 0.3f;
  int s0 = (int)ceilf(s - 1.6f);
  if (s0 < 0) s0 = 0;
  si = s0;
  float sum = 0.f;
#pragma unroll
  for (int j = 0; j < 4; ++j) {
    const int i = s0 + j;
    float ww = 0.f;
    if (i <= 15) {
      const float d = fabsf(s - (float)i) * (1.0f / 1.6f);
      ww = fmaxf(0.f, 1.f - d);
    }
    w[j] = ww;
    sum += ww;
  }
  const float inv = 1.f / sum;
#pragma unroll
  for (int j = 0; j < 4; ++j) w[j] *= inv;
}

// -------- fused: bilinear+softmax for job j's 2 batches, then wsum -----------
static __device__ void attn_wsum_job(const MegaArgs& a, int j, char* arena) {
  float* sm = (float*)arena;              // 512 floats
  float* at = (float*)(arena + 2048);     // 2 x 128 floats
  const int tid = threadIdx.x;
  const int sub = tid >> 8, st = tid & 255;
  const int b = j * 2 + sub;
  float val = -1e30f;
  if (st < 100) {
    const int oy = st / 10, ox = st - oy * 10;
    int siy, six;
    float wy[4], wx[4];
    taps(oy, siy, wy);
    taps(ox, six, wx);
    const float* p = a.a4 + (b << 8);
    float s = 0.f;
#pragma unroll
    for (int jy = 0; jy < 4; ++jy) {
      const int iy = min(siy + jy, 15);
      float rs = 0.f;
#pragma unroll
      for (int jx = 0; jx < 4; ++jx) {
        const int ix = min(six + jx, 15);
        rs += wx[jx] * p[(iy << 4) + ix];
      }
      s += wy[jy] * rs;
    }
    val = s;
  }
  sm[tid] = val;
  __syncthreads();
  for (int off = 128; off > 0; off >>= 1) {
    if (st < off) sm[tid] = fmaxf(sm[tid], sm[tid + off]);
    __syncthreads();
  }
  const float mxv = sm[sub << 8];
  __syncthreads();
  const float e = (st < 100) ? expf(val - mxv) : 0.f;
  sm[tid] = e;
  __syncthreads();
  for (int off = 128; off > 0; off >>= 1) {
    if (st < off) sm[tid] += sm[tid + off];
    __syncthreads();
  }
  if (st < 100) at[(sub << 7) + st] = e / sm[sub << 8];
  __syncthreads();
  // ---- wsum for batch b ----
  const int d0 = st << 2;
  float s0 = 0, s1 = 0, s2 = 0, s3 = 0;
  if (a.use_fmb) {
    const u16* p = a.fmb + (size_t)b * 102400 + d0;
    for (int pp = 0; pp < 100; ++pp) {
      const ushort4 v = *(const ushort4*)(p + pp * 1024);
      const float aa = at[(sub << 7) + pp];
      s0 += aa * bf2f(v.x); s1 += aa * bf2f(v.y); s2 += aa * bf2f(v.z); s3 += aa * bf2f(v.w);
    }
  } else {
    const float* p = a.fm + (size_t)b * 102400 + d0;
    for (int pp = 0; pp < 100; ++pp) {
      const float4 v = *(const float4*)(p + pp * 1024);
      const float aa = at[(sub << 7) + pp];
      s0 += aa * v.x; s1 += aa * v.y; s2 += aa * v.z; s3 += aa * v.w;
    }
  }
  const int o = (b << 10) + d0;
  float4 vs = *(float4*)(a.vis_sum + o);
  vs.x += s0; vs.y += s1; vs.z += s2; vs.w += s3;
  *(float4*)(a.vis_sum + o) = vs;
  ushort4 u; u.x = f2bf(s0); u.y = f2bf(s1); u.z = f2bf(s2); u.w = f2bf(s3);
  *(ushort4*)(a.visb + o) = u;
  ushort4 w; w.x = f2bf(vs.x); w.y = f2bf(vs.y); w.z = f2bf(vs.z); w.w = f2bf(vs.w);
  *(ushort4*)(a.vsb + o) = w;
  __syncthreads();  // at/sm reuse by next job
}

// -------- the mega kernel: whole net, one launch --------
__global__ __launch_bounds__(THREADS) void mega_k(MegaArgs a) {
  __shared__ char arena[65536];
  u16* au = (u16*)arena;
  const int tid = threadIdx.x;
  const int bid = blockIdx.x;
  const int grp = bid & 7;
  int ep = 0;

  // ---- PS1: fm_pass + weight transposes + convT packing + misc ----
  for (int j = bid; j < 3024; j += GRID) {
    if (j < 512) {
      const int sub = tid >> 8, st = tid & 255;
      fm_body(a, j * 2 + sub, st);
    } else if (j < 2352) {
      const int sub = tid >> 8, st = tid & 255;
      prep_body(a, (j - 512) * 2 + sub, st, (float(*)[65])(arena + sub * 16640));
    } else if (j < 2608) {
      const int base = (j - 2352) * 8192;
#pragma unroll
      for (int r = 0; r < 16; ++r) misc_elem(base + r * 512 + tid, a);
    } else {
      const long base = (long)(j - 2608) * 8192;
#pragma unroll
      for (int r = 0; r < 16; ++r) build_elem(base + r * 512 + tid, a);
    }
    __syncthreads();
  }
  ++ep; gbar2(a.ctrl, grp, ep);

  // ---- PS2: P1 = nonvis@W1nv + b1 (256 tiles); snv = nonvis@Wsnv + bs ----
  for (int j = bid; j < 272; j += GRID) {
    if (j < 256)
      gtile128<E_BIAS | E_WF32>(au, a.nonvis_b, a.W1nv_t, a.P1, nullptr, nullptr,
                                a.b1, nullptr, nullptr, 2048, 2048, j & 15, j >> 4);
    else
      gtile128<E_BIAS | E_WF32>(au, a.nonvis_b, a.Wsnv_t, a.snv, nullptr, nullptr,
                                a.bs_pad, nullptr, nullptr, 128, 2048, 0, j - 256);
  }
  ++ep; gbar2(a.ctrl, grp, ep);

  // ---- 5 iterations ----
  for (int it = 0; it < 5; ++it) {
    // PA: x1 = bn(relu(visb@W1v + P1))   (512 jobs, 2/block)
    for (int j = bid; j < 512; j += GRID)
      gtile64<E_CADD | E_RELU | E_AFF | E_WBF>(au, a.visb, a.W1v_t, nullptr, a.x1,
                                               a.P1, nullptr, a.scale1, a.shift1,
                                               2048, 1024, j & 31, j >> 5);
    ++ep; gbar2(a.ctrl, grp, ep);
    // PB: x2 = bn(relu(x1@W2 + b2))   (256 jobs)
    for (int j = bid; j < 256; j += GRID)
      gtile64<E_BIAS | E_RELU | E_AFF | E_WBF>(au, a.x1, a.W2t, nullptr, a.x2,
                                               nullptr, a.b2, a.scale2, a.shift2,
                                               1024, 2048, j & 15, j >> 4);
    ++ep; gbar2(a.ctrl, grp, ep);
    // PC: mx = x2@Wk + bi   (768 jobs, 3/block)
    for (int j = bid; j < 768; j += GRID)
      gtile64<E_BIAS | E_WF32>(au, a.x2, a.Wkt, a.mx, nullptr, nullptr, a.bi,
                               nullptr, nullptr, 3072, 1024, j % 48, j / 48);
    ++ep; gbar2(a.ctrl, grp, ep);
    // PD: gru (it==0: mi == br since h==0)
    for (int i = bid * THREADS + tid; i < 1048576; i += GRID * THREADS)
      gru_elem(i, a, it);
    ++ep; gbar2(a.ctrl, grp, ep);
    // PE: c1 = relu(hb@Wp1 + bp1) (256) + mi' = hb@Uk + br (768) -> 4/block
    {
      const int nj = (it < 4) ? 1024 : 256;
      for (int j = bid; j < nj; j += GRID) {
        if (j < 256)
          gtile64<E_BIAS | E_RELU | E_WBF>(au, a.hb, a.Wp1, nullptr, a.a1,
                                           nullptr, a.bp1, nullptr, nullptr,
                                           1024, 1024, j & 15, j >> 4);
        else {
          const int t2 = j - 256;
          gtile64<E_BIAS | E_WF32>(au, a.hb, a.Ukt, a.mi, nullptr, nullptr, a.br,
                                   nullptr, nullptr, 3072, 1024, t2 % 48, t2 / 48);
        }
      }
    }
    ++ep; gbar2(a.ctrl, grp, ep);
    // PF: c2   (256 jobs)
    for (int j = bid; j < 256; j += GRID)
      gtile64<E_BIAS | E_RELU | E_WBF>(au, a.a1, a.Wp2, nullptr, a.a2, nullptr,
                                       a.bp2, nullptr, nullptr, 1024, 1024, j & 15, j >> 4);
    ++ep; gbar2(a.ctrl, grp, ep);
    // PG: c3   (256 jobs)
    for (int j = bid; j < 256; j += GRID)
      gtile64<E_BIAS | E_RELU | E_WBF>(au, a.a2, a.Wp3, nullptr, a.a3, nullptr,
                                       a.bp3, nullptr, nullptr, 1024, 1024, j & 15, j >> 4);
    ++ep; gbar2(a.ctrl, grp, ep);
    // PH: c4 -> a4 (1024 x 256 fp32)   (64 jobs)
    for (int j = bid; j < 64; j += GRID)
      gtile64<E_BIAS | E_WF32>(au, a.a3, a.Wp4, a.a4, nullptr, nullptr, a.bp4,
                               nullptr, nullptr, 256, 1024, j & 3, j >> 2);
    ++ep; gbar2(a.ctrl, grp, ep);
    // PIJ: bilinear+softmax (in-LDS) then wsum; 512 jobs x 2 batches
    for (int j = bid; j < 512; j += GRID)
      attn_wsum_job(a, j, arena);
    ++ep; gbar2(a.ctrl, grp, ep);
  }

  // PZ: out = (vsb@Wsv)/6 + snv + prior  (fused epilogue)
  for (int j = bid; j < 16; j += GRID)
    gtile128<E_FINAL>(au, a.vsb, a.Wsv_t, a.out, nullptr, a.snv, nullptr,
                      a.prior, nullptr, 128, 1024, 0, j);
}

extern "C" void kernel_launch(void* const* d_in, const int* in_sizes, int n_in,
                              void* d_out, int out_size, void* d_ws, size_t ws_size,
                              hipStream_t stream) {
  (void)in_sizes; (void)n_in; (void)out_size;
  MegaArgs a;
  a.nonvis = (const float*)d_in[0];  a.fm   = (const float*)d_in[1];
  a.prior  = (const float*)d_in[2];  a.W1   = (const float*)d_in[3];
  a.b1  = (const float*)d_in[4];     a.g1   = (const float*)d_in[5];
  a.be1 = (const float*)d_in[6];     a.m1   = (const float*)d_in[7];
  a.v1  = (const float*)d_in[8];     a.W2   = (const float*)d_in[9];
  a.b2  = (const float*)d_in[10];    a.g2   = (const float*)d_in[11];
  a.be2 = (const float*)d_in[12];    a.m2   = (const float*)d_in[13];
  a.v2  = (const float*)d_in[14];    a.Wk   = (const float*)d_in[15];
  a.Uk  = (const float*)d_in[16];    a.bi   = (const float*)d_in[17];
  a.br  = (const float*)d_in[18];    a.ct1w = (const float*)d_in[19];
  a.ct1b = (const float*)d_in[20];   a.ct2w = (const float*)d_in[21];
  a.ct2b = (const float*)d_in[22];   a.ct3w = (const float*)d_in[23];
  a.ct3b = (const float*)d_in[24];   a.ct4w = (const float*)d_in[25];
  a.ct4b = (const float*)d_in[26];   a.Ws   = (const float*)d_in[27];
  a.bs  = (const float*)d_in[28];

  char* base = (char*)d_ws;
  size_t off = 0;
  auto alloc = [&](size_t bytes) -> void* {
    void* r = base + off;
    off = (off + bytes + 255) & ~(size_t)255;
    return r;
  };

  a.ctrl     = (unsigned*)alloc(4096);
  a.nonvis_b = (u16*)alloc(4194304);
  a.W1nv_t   = (u16*)alloc(8388608);
  a.W1v_t    = (u16*)alloc(4194304);
  a.W2t      = (u16*)alloc(4194304);
  a.Wkt      = (u16*)alloc(6291456);
  a.Ukt      = (u16*)alloc(6291456);
  a.Wsnv_t   = (u16*)alloc(524288);
  a.Wsv_t    = (u16*)alloc(262144);
  a.Wp1      = (u16*)alloc(2097152);
  a.Wp2      = (u16*)alloc(2097152);
  a.Wp3      = (u16*)alloc(2097152);
  a.Wp4      = (u16*)alloc(524288);
  a.bp1      = (float*)alloc(4096);
  a.bp2      = (float*)alloc(4096);
  a.bp3      = (float*)alloc(4096);
  a.bp4      = (float*)alloc(1024);
  a.scale1   = (float*)alloc(8192);
  a.shift1   = (float*)alloc(8192);
  a.scale2   = (float*)alloc(4096);
  a.shift2   = (float*)alloc(4096);
  a.bs_pad   = (float*)alloc(512);
  a.P1       = (float*)alloc(8388608);
  a.snv      = (float*)alloc(524288);
  a.x1       = (u16*)alloc(4194304);
  a.x2       = (u16*)alloc(2097152);
  a.mx       = (float*)alloc(12582912);
  a.mi       = (float*)alloc(12582912);
  a.hf       = (float*)alloc(4194304);
  a.hb       = (u16*)alloc(2097152);
  a.a1       = (u16*)alloc(2097152);
  a.a2       = (u16*)alloc(2097152);
  a.a3       = (u16*)alloc(2097152);
  a.a4       = (float*)alloc(1048576);
  a.vis_sum  = (float*)alloc(4194304);
  a.visb     = (u16*)alloc(2097152);
  a.vsb      = (u16*)alloc(2097152);
  a.out      = (float*)d_out;
  a.fmb = nullptr;
  a.use_fmb = 0;
  if (off + (size_t)209715200 + 256 <= ws_size) {
    a.fmb = (u16*)alloc(209715200);
    a.use_fmb = 1;
  }

  hipMemsetAsync(a.ctrl, 0, 4096, stream);
  mega_k<<<GRID, THREADS, 0, stream>>>(a);
}

// Round 10
// 1454.796 us; speedup vs baseline: 4.2943x; 1.1065x over previous
//
#include <hip/hip_runtime.h>

typedef unsigned short u16;
typedef __attribute__((ext_vector_type(8))) __bf16 bf16x8;
typedef __attribute__((ext_vector_type(4))) float f32x4;

typedef __attribute__((address_space(1))) const void gvoid_t;
typedef __attribute__((address_space(3))) void lvoid_t;

enum { E_CADD = 1, E_BIAS = 2, E_RELU = 4, E_AFF = 8, E_WBF = 16, E_WF32 = 32, E_FINAL = 64 };

#define GRID 256
#define THREADS 512

static __device__ __forceinline__ u16 f2bf(float f) {
  unsigned u = __float_as_uint(f);
  u += 0x7fffu + ((u >> 16) & 1u);
  return (u16)(u >> 16);
}
static __device__ __forceinline__ float bf2f(u16 h) {
  return __uint_as_float(((unsigned)h) << 16);
}

struct MegaArgs {
  const float *nonvis, *fm, *prior, *W1, *b1, *g1, *be1, *m1, *v1;
  const float *W2, *b2, *g2, *be2, *m2, *v2, *Wk, *Uk, *bi, *br;
  const float *ct1w, *ct1b, *ct2w, *ct2b, *ct3w, *ct3b, *ct4w, *ct4b, *Ws, *bs;
  u16 *nonvis_b, *W1nv_t, *W1v_t, *W2t, *Wkt, *Ukt, *Wsnv_t, *Wsv_t;
  u16 *Wp1, *Wp2, *Wp3, *Wp4;
  float *bp1, *bp2, *bp3, *bp4, *scale1, *shift1, *scale2, *shift2, *bs_pad;
  float *P1, *snv, *mx, *mi, *hf;
  u16 *x1, *x2, *hb, *a1, *a2, *a3;
  float *a4, *vis_sum;
  u16 *visb, *vsb, *fmb;
  float *out;
  unsigned *ctrl;
  int use_fmb;
};

// ---- two-level GLOBAL barrier (R6-proven) — used exactly ONCE ---------------
static __device__ __forceinline__ void gbar2(unsigned* ctrl, int grp, int ep) {
  __syncthreads();
  if (threadIdx.x == 0) {
    unsigned* xc = ctrl + 32 + 32 * grp;
    unsigned* xf = ctrl + 320 + 32 * grp;
    const unsigned old =
        __hip_atomic_fetch_add(xc, 1u, __ATOMIC_RELEASE, __HIP_MEMORY_SCOPE_AGENT);
    if (old == (unsigned)(ep * 32 - 1)) {
      __hip_atomic_fetch_add(ctrl, 1u, __ATOMIC_RELAXED, __HIP_MEMORY_SCOPE_AGENT);
      while (__hip_atomic_load(ctrl, __ATOMIC_RELAXED, __HIP_MEMORY_SCOPE_AGENT) <
             (unsigned)(ep * 8))
        __builtin_amdgcn_s_sleep(2);
      (void)__hip_atomic_load(ctrl, __ATOMIC_ACQUIRE, __HIP_MEMORY_SCOPE_AGENT);
      __hip_atomic_store(xf, (unsigned)ep, __ATOMIC_RELAXED, __HIP_MEMORY_SCOPE_AGENT);
    } else {
      while (__hip_atomic_load(xf, __ATOMIC_RELAXED, __HIP_MEMORY_SCOPE_AGENT) <
             (unsigned)ep)
        __builtin_amdgcn_s_sleep(2);
      (void)__hip_atomic_load(xf, __ATOMIC_ACQUIRE, __HIP_MEMORY_SCOPE_AGENT);
    }
  }
  __syncthreads();
}

// ---- BAND-local barrier: 16 blocks of one row-band, private cacheline -------
static __device__ __forceinline__ void bbar(unsigned* ctrl, int band, int ep) {
  __syncthreads();
  if (threadIdx.x == 0) {
    unsigned* xc = ctrl + 1024 + 32 * band;
    __hip_atomic_fetch_add(xc, 1u, __ATOMIC_RELEASE, __HIP_MEMORY_SCOPE_AGENT);
    while (__hip_atomic_load(xc, __ATOMIC_RELAXED, __HIP_MEMORY_SCOPE_AGENT) <
           (unsigned)(ep * 16))
      __builtin_amdgcn_s_sleep(1);
    (void)__hip_atomic_load(xc, __ATOMIC_ACQUIRE, __HIP_MEMORY_SCOPE_AGENT);
  }
  __syncthreads();
}

// -------- 64x128 MFMA tile, 8 waves (32x32 each, 2x2 acc), 4-buffer 3-deep ---
// pipeline, counted vmcnt (3 loads/stage => steady wait vmcnt(6)).
// LDS: 4 buffers x 12288 elems x 2B = 98304 bytes (R9 bug: arena was 48KB).
template <int FLAGS>
static __device__ void gtileP(u16* au,
    const u16* __restrict__ A, const u16* __restrict__ Bt,
    float* __restrict__ Cf, u16* __restrict__ Cb,
    const float* __restrict__ Cadd, const float* __restrict__ bias,
    const float* __restrict__ scale, const float* __restrict__ shift,
    int N, int K, int bx, int by) {
  const int tid = threadIdx.x;
  const int wave = tid >> 6, lane = tid & 63;
  const int bm = by << 6, bn = bx << 7;
  const int lr = lane & 15, lg = lane >> 4;
  const int rx = lr & 7;
  const int wm = (wave >> 2) << 5, wn = (wave & 3) << 5;

  f32x4 acc[2][2] = {};

  const int rowA = tid >> 3;
  const int cg = (tid & 7) ^ (rowA & 7);          // (row+64)&7 == row&7: same cg for B1
  const u16* gA = A + (size_t)(bm + rowA) * K + (cg << 3);
  const u16* gB0 = Bt + (size_t)(bn + rowA) * K + (cg << 3);
  const u16* gB1 = Bt + (size_t)(bn + 64 + rowA) * K + (cg << 3);
  const int lofs = wave * 512;                    // wave-uniform LDS base (elems)

  auto stage = [&](int buf, int kt) {
    u16* base = au + buf * 12288;
    __builtin_amdgcn_global_load_lds((gvoid_t*)(gA + kt), (lvoid_t*)(base + lofs), 16, 0, 0);
    __builtin_amdgcn_global_load_lds((gvoid_t*)(gB0 + kt), (lvoid_t*)(base + 4096 + lofs), 16, 0, 0);
    __builtin_amdgcn_global_load_lds((gvoid_t*)(gB1 + kt), (lvoid_t*)(base + 8192 + lofs), 16, 0, 0);
  };

  stage(0, 0); stage(1, 64); stage(2, 128);
  const int nsteps = K >> 6;
  for (int s = 0; s < nsteps; ++s) {
    const int rem = nsteps - 1 - s;
    if (rem >= 2)      asm volatile("s_waitcnt vmcnt(6)" ::: "memory");
    else if (rem == 1) asm volatile("s_waitcnt vmcnt(3)" ::: "memory");
    else               asm volatile("s_waitcnt vmcnt(0)" ::: "memory");
    __builtin_amdgcn_s_barrier();
    if (s + 3 < nsteps) stage((s + 3) & 3, (s + 3) << 6);
    const u16* Ab = au + (s & 3) * 12288;
    const u16* Bb = Ab + 4096;
#pragma unroll
    for (int kk = 0; kk < 64; kk += 32) {
      const int sw = ((((kk >> 3) + lg) ^ rx) << 3);
      bf16x8 av0 = *(const bf16x8*)(Ab + ((wm + lr) << 6) + sw);
      bf16x8 av1 = *(const bf16x8*)(Ab + ((wm + 16 + lr) << 6) + sw);
      bf16x8 bv0 = *(const bf16x8*)(Bb + ((wn + lr) << 6) + sw);
      bf16x8 bv1 = *(const bf16x8*)(Bb + ((wn + 16 + lr) << 6) + sw);
      acc[0][0] = __builtin_amdgcn_mfma_f32_16x16x32_bf16(av0, bv0, acc[0][0], 0, 0, 0);
      acc[0][1] = __builtin_amdgcn_mfma_f32_16x16x32_bf16(av0, bv1, acc[0][1], 0, 0, 0);
      acc[1][0] = __builtin_amdgcn_mfma_f32_16x16x32_bf16(av1, bv0, acc[1][0], 0, 0, 0);
      acc[1][1] = __builtin_amdgcn_mfma_f32_16x16x32_bf16(av1, bv1, acc[1][1], 0, 0, 0);
    }
  }

#pragma unroll
  for (int mi2 = 0; mi2 < 2; ++mi2) {
#pragma unroll
    for (int ni = 0; ni < 2; ++ni) {
      const int col = bn + wn + ni * 16 + lr;
#pragma unroll
      for (int r = 0; r < 4; ++r) {
        const int rw = bm + wm + mi2 * 16 + (lg << 2) + r;
        float v = acc[mi2][ni][r];
        if (FLAGS & E_FINAL) {
          if (col < 51)
            Cf[rw * 51 + col] = v * (1.f / 6.f) + Cadd[(rw << 7) + col] + scale[rw * 51 + col];
        } else {
          if (FLAGS & E_CADD) v += Cadd[(size_t)rw * N + col];
          if (FLAGS & E_BIAS) v += bias[col];
          if (FLAGS & E_RELU) v = fmaxf(v, 0.f);
          if (FLAGS & E_AFF) v = v * scale[col] + shift[col];
          if (FLAGS & E_WF32) Cf[(size_t)rw * N + col] = v;
          if (FLAGS & E_WBF) Cb[(size_t)rw * N + col] = f2bf(v);
        }
      }
    }
  }
  __syncthreads();                       // all reads of buf 3 done before reuse
}

// -------- phase bodies --------
static __device__ void fm_body(const MegaArgs& a, int b, int st) {
  const int d0 = st << 2;
  const float* p = a.fm + (size_t)b * 102400 + d0;
  float s0 = 0, s1 = 0, s2 = 0, s3 = 0;
  for (int pp = 0; pp < 100; ++pp) {
    const float4 v = *(const float4*)(p + pp * 1024);
    if (a.use_fmb) {
      ushort4 u;
      u.x = f2bf(v.x); u.y = f2bf(v.y); u.z = f2bf(v.z); u.w = f2bf(v.w);
      *(ushort4*)(a.fmb + (size_t)b * 102400 + pp * 1024 + d0) = u;
    }
    s0 += v.x; s1 += v.y; s2 += v.z; s3 += v.w;
  }
  const float inv = 1.0f / 100.0f;
  s0 *= inv; s1 *= inv; s2 *= inv; s3 *= inv;
  const int o = (b << 10) + d0;
  float4 m; m.x = s0; m.y = s1; m.z = s2; m.w = s3;
  *(float4*)(a.vis_sum + o) = m;
  ushort4 u; u.x = f2bf(s0); u.y = f2bf(s1); u.z = f2bf(s2); u.w = f2bf(s3);
  *(ushort4*)(a.visb + o) = u;
}

static __device__ void prep_body(const MegaArgs& a, int b, int st, float (*t)[65]) {
  const float* in; u16* out; int ld, k0, K, Nv, kT;
  int bb = b;
  if (bb < 1024)      {            in = a.W1; out = a.W1nv_t; ld = 2048; k0 = 0;    K = 2048; Nv = 2048; kT = 32; }
  else if (bb < 1536) { bb -= 1024; in = a.W1; out = a.W1v_t;  ld = 2048; k0 = 2048; K = 1024; Nv = 2048; kT = 16; }
  else if (bb < 2048) { bb -= 1536; in = a.W2; out = a.W2t;   ld = 1024; k0 = 0;    K = 2048; Nv = 1024; kT = 32; }
  else if (bb < 2816) { bb -= 2048; in = a.Wk; out = a.Wkt;   ld = 3072; k0 = 0;    K = 1024; Nv = 3072; kT = 16; }
  else if (bb < 3584) { bb -= 2816; in = a.Uk; out = a.Ukt;   ld = 3072; k0 = 0;    K = 1024; Nv = 3072; kT = 16; }
  else if (bb < 3648) { bb -= 3584; in = a.Ws; out = a.Wsnv_t; ld = 51;  k0 = 0;    K = 2048; Nv = 51;   kT = 32; }
  else                { bb -= 3648; in = a.Ws; out = a.Wsv_t;  ld = 51;  k0 = 2048; K = 1024; Nv = 51;   kT = 16; }
  const int kt = (bb % kT) << 6, nt = (bb / kT) << 6;
  const int tx = st & 63, ty = st >> 6;
#pragma unroll
  for (int i = 0; i < 16; ++i) {
    const int kl = ty + i * 4;
    const int n = nt + tx;
    t[kl][tx] = (n < Nv) ? in[(size_t)(k0 + kt + kl) * ld + n] : 0.f;
  }
  __syncthreads();
#pragma unroll
  for (int i = 0; i < 16; ++i)
    out[(size_t)(nt + ty + i * 4) * K + kt + tx] = f2bf(t[tx][ty + i * 4]);
}

static __device__ void misc_w(int i, const MegaArgs& a) {
  if (i < 2048) { float sc = a.g1[i] * rsqrtf(a.v1[i] + 1e-3f); a.scale1[i] = sc; a.shift1[i] = a.be1[i] - a.m1[i] * sc; }
  if (i < 1024) { float sc = a.g2[i] * rsqrtf(a.v2[i] + 1e-3f); a.scale2[i] = sc; a.shift2[i] = a.be2[i] - a.m2[i] * sc; }
  if (i < 128) a.bs_pad[i] = (i < 51) ? a.bs[i] : 0.f;
}

// convT weight packing: even out-pixel p: w[0]*x[p/2-1] + w[2]*x[p/2]; odd: w[1]*x[(p-1)/2]
static __device__ void build_elem(long idx, const MegaArgs& a) {
  const float* w; const float* bin; u16* wp; float* bp; int Si, CI, CO; long base;
  if (idx < 1048576)      { base = 0;       w = a.ct1w; bin = a.ct1b; wp = a.Wp1; bp = a.bp1; Si = 1; CI = 1024; CO = 256; }
  else if (idx < 2097152) { base = 1048576; w = a.ct2w; bin = a.ct2b; wp = a.Wp2; bp = a.bp2; Si = 2; CI = 256;  CO = 64; }
  else if (idx < 3145728) { base = 2097152; w = a.ct3w; bin = a.ct3b; wp = a.Wp3; bp = a.bp3; Si = 4; CI = 64;   CO = 16; }
  else                    { base = 3145728; w = a.ct4w; bin = a.ct4b; wp = a.Wp4; bp = a.bp4; Si = 8; CI = 16;   CO = 1; }
  const long r = idx - base;
  const int n = (int)(r >> 10), k = (int)(r & 1023);
  const int So = Si * 2;
  const int co = n % CO;
  const int pox = (n / CO) % So;
  const int poy = n / (CO * So);
  const int ci = k % CI;
  const int pix = (k / CI) % Si;
  const int piy = k / (CI * Si);
  int wy = -1, wx = -1;
  if (poy & 1) { if (piy == (poy >> 1)) wy = 1; }
  else { if (piy == (poy >> 1)) wy = 2; else if (piy == (poy >> 1) - 1) wy = 0; }
  if (pox & 1) { if (pix == (pox >> 1)) wx = 1; }
  else { if (pix == (pox >> 1)) wx = 2; else if (pix == (pox >> 1) - 1) wx = 0; }
  float v = 0.f;
  if (wy >= 0 && wx >= 0) v = w[((size_t)(wy * 3 + wx) * CI + ci) * CO + co];
  wp[(size_t)n * 1024 + k] = f2bf(v);
  if (k == 0) bp[n] = bin[co];
}

static __device__ void gru_elem(int idx, const MegaArgs& a, int it) {
  const int b = idx >> 10, d = idx & 1023;
  const float* mxb = a.mx + (size_t)b * 3072;
  const float xz = mxb[d], xr = mxb[d + 1024], xh = mxb[d + 2048];
  float iz, ir, ih;
  if (it == 0) { iz = a.br[d]; ir = a.br[d + 1024]; ih = a.br[d + 2048]; }
  else {
    const float* mib = a.mi + (size_t)b * 3072;
    iz = mib[d]; ir = mib[d + 1024]; ih = mib[d + 2048];
  }
  const float zg = 1.f / (1.f + expf(-(xz + iz)));
  const float rg = 1.f / (1.f + expf(-(xr + ir)));
  const float hh = tanhf(xh + rg * ih);
  const float hn = zg * a.hf[idx] + (1.f - zg) * hh;
  a.hf[idx] = hn;
  a.hb[idx] = f2bf(hn);
}

static __device__ __forceinline__ void taps(int o, int& si, float* w) {
  const float s = 1.6f * (float)o + 0.3f;
  int s0 = (int)ceilf(s - 1.6f);
  if (s0 < 0) s0 = 0;
  si = s0;
  float sum = 0.f;
#pragma unroll
  for (int j = 0; j < 4; ++j) {
    const int i = s0 + j;
    float ww = 0.f;
    if (i <= 15) {
      const float d = fabsf(s - (float)i) * (1.0f / 1.6f);
      ww = fmaxf(0.f, 1.f - d);
    }
    w[j] = ww;
    sum += ww;
  }
  const float inv = 1.f / sum;
#pragma unroll
  for (int j = 0; j < 4; ++j) w[j] *= inv;
}

// -------- fused: bilinear+softmax for job j's 2 batches, then wsum -----------
static __device__ void attn_wsum_job(const MegaArgs& a, int j, char* arena) {
  float* sm = (float*)arena;              // 512 floats
  float* at = (float*)(arena + 2048);     // 2 x 128 floats
  const int tid = threadIdx.x;
  const int sub = tid >> 8, st = tid & 255;
  const int b = j * 2 + sub;
  float val = -1e30f;
  if (st < 100) {
    const int oy = st / 10, ox = st - oy * 10;
    int siy, six;
    float wy[4], wx[4];
    taps(oy, siy, wy);
    taps(ox, six, wx);
    const float* p = a.a4 + (b << 8);
    float s = 0.f;
#pragma unroll
    for (int jy = 0; jy < 4; ++jy) {
      const int iy = min(siy + jy, 15);
      float rs = 0.f;
#pragma unroll
      for (int jx = 0; jx < 4; ++jx) {
        const int ix = min(six + jx, 15);
        rs += wx[jx] * p[(iy << 4) + ix];
      }
      s += wy[jy] * rs;
    }
    val = s;
  }
  sm[tid] = val;
  __syncthreads();
  for (int off = 128; off > 0; off >>= 1) {
    if (st < off) sm[tid] = fmaxf(sm[tid], sm[tid + off]);
    __syncthreads();
  }
  const float mxv = sm[sub << 8];
  __syncthreads();
  const float e = (st < 100) ? expf(val - mxv) : 0.f;
  sm[tid] = e;
  __syncthreads();
  for (int off = 128; off > 0; off >>= 1) {
    if (st < off) sm[tid] += sm[tid + off];
    __syncthreads();
  }
  if (st < 100) at[(sub << 7) + st] = e / sm[sub << 8];
  __syncthreads();
  // ---- wsum for batch b ----
  const int d0 = st << 2;
  float s0 = 0, s1 = 0, s2 = 0, s3 = 0;
  if (a.use_fmb) {
    const u16* p = a.fmb + (size_t)b * 102400 + d0;
    for (int pp = 0; pp < 100; ++pp) {
      const ushort4 v = *(const ushort4*)(p + pp * 1024);
      const float aa = at[(sub << 7) + pp];
      s0 += aa * bf2f(v.x); s1 += aa * bf2f(v.y); s2 += aa * bf2f(v.z); s3 += aa * bf2f(v.w);
    }
  } else {
    const float* p = a.fm + (size_t)b * 102400 + d0;
    for (int pp = 0; pp < 100; ++pp) {
      const float4 v = *(const float4*)(p + pp * 1024);
      const float aa = at[(sub << 7) + pp];
      s0 += aa * v.x; s1 += aa * v.y; s2 += aa * v.z; s3 += aa * v.w;
    }
  }
  const int o = (b << 10) + d0;
  float4 vs = *(float4*)(a.vis_sum + o);
  vs.x += s0; vs.y += s1; vs.z += s2; vs.w += s3;
  *(float4*)(a.vis_sum + o) = vs;
  ushort4 u; u.x = f2bf(s0); u.y = f2bf(s1); u.z = f2bf(s2); u.w = f2bf(s3);
  *(ushort4*)(a.visb + o) = u;
  ushort4 w; w.x = f2bf(vs.x); w.y = f2bf(vs.y); w.z = f2bf(vs.z); w.w = f2bf(vs.w);
  *(ushort4*)(a.vsb + o) = w;
  __syncthreads();  // at/sm reuse by next job
}

// -------- the mega kernel: ONE global barrier, then 16 async row-bands -------
__global__ __launch_bounds__(THREADS) void mega_k(MegaArgs a) {
  __shared__ char arena[98304];    // 4 x 24KB gtileP buffers (R9 bug: was 48KB)
  u16* au = (u16*)arena;
  const int tid = threadIdx.x;
  const int bid = blockIdx.x;
  const int band = bid >> 4;       // 16 bands x 64 batch rows
  const int lb = bid & 15;         // block index within band
  const int br0 = band << 6;       // first batch row of band
  int bep = 0;

  // ---- GLOBAL SETUP: weights only (transposes + convT packing + BN consts) --
  for (int j = bid; j < 2257; j += GRID) {
    if (j < 1840) {
      const int sub = tid >> 8, st = tid & 255;
      prep_body(a, j * 2 + sub, st, (float(*)[65])(arena + sub * 16640));
    } else if (j < 2256) {
      const long base = (long)(j - 1840) * 8192;
#pragma unroll
      for (int r = 0; r < 16; ++r) build_elem(base + r * 512 + tid, a);
    } else {
#pragma unroll
      for (int r = 0; r < 4; ++r) misc_w(r * 512 + tid, a);
    }
    __syncthreads();
  }
  gbar2(a.ctrl, bid & 7, 1);   // the ONLY global barrier

  // ---- BAND SETUP: fm mean+bf16 copy, nonvis cast, h init (all row-local) ---
  for (int j = lb; j < 32; j += 16) {
    const int sub = tid >> 8, st = tid & 255;
    fm_body(a, br0 + j * 2 + sub, st);
  }
  for (int i = (lb << 9) + tid; i < 131072; i += 8192) {
    const int idx = (band << 17) + i;
    a.nonvis_b[idx] = f2bf(a.nonvis[idx]);
  }
  for (int i = (lb << 9) + tid; i < 65536; i += 8192) {
    const int idx = (band << 16) + i;
    a.hf[idx] = 0.f; a.hb[idx] = 0;
  }
  ++bep; bbar(a.ctrl, band, bep);

  // ---- PS2-band: P1 rows (16 col tiles) + snv (1 tile) ----
  for (int j = lb; j < 17; j += 16) {
    if (j < 16)
      gtileP<E_BIAS | E_WF32>(au, a.nonvis_b, a.W1nv_t, a.P1, nullptr, nullptr,
                              a.b1, nullptr, nullptr, 2048, 2048, j, band);
    else
      gtileP<E_BIAS | E_WF32>(au, a.nonvis_b, a.Wsnv_t, a.snv, nullptr, nullptr,
                              a.bs_pad, nullptr, nullptr, 128, 2048, 0, band);
  }
  ++bep; bbar(a.ctrl, band, bep);

  // ---- 5 iterations, fully band-local ----
  for (int it = 0; it < 5; ++it) {
    // PA: x1 = bn(relu(visb@W1v + P1))   16 col tiles
    gtileP<E_CADD | E_RELU | E_AFF | E_WBF>(au, a.visb, a.W1v_t, nullptr, a.x1,
                                            a.P1, nullptr, a.scale1, a.shift1,
                                            2048, 1024, lb, band);
    ++bep; bbar(a.ctrl, band, bep);
    // PB: x2 = bn(relu(x1@W2 + b2))   8 col tiles
    if (lb < 8)
      gtileP<E_BIAS | E_RELU | E_AFF | E_WBF>(au, a.x1, a.W2t, nullptr, a.x2,
                                              nullptr, a.b2, a.scale2, a.shift2,
                                              1024, 2048, lb, band);
    ++bep; bbar(a.ctrl, band, bep);
    // PC: mx = x2@Wk + bi   24 col tiles
    for (int j = lb; j < 24; j += 16)
      gtileP<E_BIAS | E_WF32>(au, a.x2, a.Wkt, a.mx, nullptr, nullptr, a.bi,
                              nullptr, nullptr, 3072, 1024, j, band);
    ++bep; bbar(a.ctrl, band, bep);
    // PD: gru for band rows (it==0: mi == br since h==0)
    for (int i = (lb << 9) + tid; i < 65536; i += 8192)
      gru_elem((band << 16) + i, a, it);
    ++bep; bbar(a.ctrl, band, bep);
    // PE: c1 = relu(hb@Wp1+bp1) (8 tiles) + mi' = hb@Uk + br (24 tiles)
    {
      const int nj = (it < 4) ? 32 : 8;
      for (int j = lb; j < nj; j += 16) {
        if (j < 8)
          gtileP<E_BIAS | E_RELU | E_WBF>(au, a.hb, a.Wp1, nullptr, a.a1,
                                          nullptr, a.bp1, nullptr, nullptr,
                                          1024, 1024, j, band);
        else
          gtileP<E_BIAS | E_WF32>(au, a.hb, a.Ukt, a.mi, nullptr, nullptr, a.br,
                                  nullptr, nullptr, 3072, 1024, j - 8, band);
      }
    }
    ++bep; bbar(a.ctrl, band, bep);
    // PF: c2   8 tiles
    if (lb < 8)
      gtileP<E_BIAS | E_RELU | E_WBF>(au, a.a1, a.Wp2, nullptr, a.a2, nullptr,
                                      a.bp2, nullptr, nullptr, 1024, 1024, lb, band);
    ++bep; bbar(a.ctrl, band, bep);
    // PG: c3   8 tiles
    if (lb < 8)
      gtileP<E_BIAS | E_RELU | E_WBF>(au, a.a2, a.Wp3, nullptr, a.a3, nullptr,
                                      a.bp3, nullptr, nullptr, 1024, 1024, lb, band);
    ++bep; bbar(a.ctrl, band, bep);
    // PH: c4 -> a4 (band rows x 256 fp32)   2 tiles
    if (lb < 2)
      gtileP<E_BIAS | E_WF32>(au, a.a3, a.Wp4, a.a4, nullptr, nullptr, a.bp4,
                              nullptr, nullptr, 256, 1024, lb, band);
    ++bep; bbar(a.ctrl, band, bep);
    // PIJ: bilinear+softmax then wsum; 32 jobs x 2 batches
    for (int j = lb; j < 32; j += 16)
      attn_wsum_job(a, (band << 5) + j, arena);
    ++bep; bbar(a.ctrl, band, bep);
  }

  // PZ-band: out rows = (vsb@Wsv)/6 + snv + prior
  if (lb == 0)
    gtileP<E_FINAL>(au, a.vsb, a.Wsv_t, a.out, nullptr, a.snv, nullptr,
                    a.prior, nullptr, 128, 1024, 0, band);
}

extern "C" void kernel_launch(void* const* d_in, const int* in_sizes, int n_in,
                              void* d_out, int out_size, void* d_ws, size_t ws_size,
                              hipStream_t stream) {
  (void)in_sizes; (void)n_in; (void)out_size;
  MegaArgs a;
  a.nonvis = (const float*)d_in[0];  a.fm   = (const float*)d_in[1];
  a.prior  = (const float*)d_in[2];  a.W1   = (const float*)d_in[3];
  a.b1  = (const float*)d_in[4];     a.g1   = (const float*)d_in[5];
  a.be1 = (const float*)d_in[6];     a.m1   = (const float*)d_in[7];
  a.v1  = (const float*)d_in[8];     a.W2   = (const float*)d_in[9];
  a.b2  = (const float*)d_in[10];    a.g2   = (const float*)d_in[11];
  a.be2 = (const float*)d_in[12];    a.m2   = (const float*)d_in[13];
  a.v2  = (const float*)d_in[14];    a.Wk   = (const float*)d_in[15];
  a.Uk  = (const float*)d_in[16];    a.bi   = (const float*)d_in[17];
  a.br  = (const float*)d_in[18];    a.ct1w = (const float*)d_in[19];
  a.ct1b = (const float*)d_in[20];   a.ct2w = (const float*)d_in[21];
  a.ct2b = (const float*)d_in[22];   a.ct3w = (const float*)d_in[23];
  a.ct3b = (const float*)d_in[24];   a.ct4w = (const float*)d_in[25];
  a.ct4b = (const float*)d_in[26];   a.Ws   = (const float*)d_in[27];
  a.bs  = (const float*)d_in[28];

  char* base = (char*)d_ws;
  size_t off = 0;
  auto alloc = [&](size_t bytes) -> void* {
    void* r = base + off;
    off = (off + bytes + 255) & ~(size_t)255;
    return r;
  };

  a.ctrl     = (unsigned*)alloc(8192);
  a.nonvis_b = (u16*)alloc(4194304);
  a.W1nv_t   = (u16*)alloc(8388608);
  a.W1v_t    = (u16*)alloc(4194304);
  a.W2t      = (u16*)alloc(4194304);
  a.Wkt      = (u16*)alloc(6291456);
  a.Ukt      = (u16*)alloc(6291456);
  a.Wsnv_t   = (u16*)alloc(524288);
  a.Wsv_t    = (u16*)alloc(262144);
  a.Wp1      = (u16*)alloc(2097152);
  a.Wp2      = (u16*)alloc(2097152);
  a.Wp3      = (u16*)alloc(2097152);
  a.Wp4      = (u16*)alloc(524288);
  a.bp1      = (float*)alloc(4096);
  a.bp2      = (float*)alloc(4096);
  a.bp3      = (float*)alloc(4096);
  a.bp4      = (float*)alloc(1024);
  a.scale1   = (float*)alloc(8192);
  a.shift1   = (float*)alloc(8192);
  a.scale2   = (float*)alloc(4096);
  a.shift2   = (float*)alloc(4096);
  a.bs_pad   = (float*)alloc(512);
  a.P1       = (float*)alloc(8388608);
  a.snv      = (float*)alloc(524288);
  a.x1       = (u16*)alloc(4194304);
  a.x2       = (u16*)alloc(2097152);
  a.mx       = (float*)alloc(12582912);
  a.mi       = (float*)alloc(12582912);
  a.hf       = (float*)alloc(4194304);
  a.hb       = (u16*)alloc(2097152);
  a.a1       = (u16*)alloc(2097152);
  a.a2       = (u16*)alloc(2097152);
  a.a3       = (u16*)alloc(2097152);
  a.a4       = (float*)alloc(1048576);
  a.vis_sum  = (float*)alloc(4194304);
  a.visb     = (u16*)alloc(2097152);
  a.vsb      = (u16*)alloc(2097152);
  a.out      = (float*)d_out;
  a.fmb = nullptr;
  a.use_fmb = 0;
  if (off + (size_t)209715200 + 256 <= ws_size) {
    a.fmb = (u16*)alloc(209715200);
    a.use_fmb = 1;
  }

  hipMemsetAsync(a.ctrl, 0, 8192, stream);
  mega_k<<<GRID, THREADS, 0, stream>>>(a);
}